// Round 1
// baseline (520.359 us; speedup 1.0000x reference)
//
#include <hip/hip_runtime.h>

#define VV 3
#define NN 6000
#define DD 512
#define HH 256
#define DYY 512
#define NPAD 6016   // 47*128

typedef unsigned short u16;
typedef __bf16 bf16x8 __attribute__((ext_vector_type(8)));
typedef float f32x4 __attribute__((ext_vector_type(4)));
typedef u16 u16x4 __attribute__((ext_vector_type(4)));

__device__ __forceinline__ u16 f2bf(float f) {
  unsigned int b = __builtin_bit_cast(unsigned int, f);
  b += 0x7FFFu + ((b >> 16) & 1u);
  return (u16)(b >> 16);
}
__device__ __forceinline__ float bf2f(u16 u) {
  unsigned int b = ((unsigned int)u) << 16;
  return __builtin_bit_cast(float, b);
}
__device__ __forceinline__ float leaky(float v) { return v >= 0.0f ? v : 0.1f * v; }

// ---- stage ROWS x 64 bf16 tile: global row-major (ld elems) -> LDS [ROWS][64], via global_load_lds width=16
template<int ROWS>
__device__ __forceinline__ void stage(const u16* __restrict__ g, int ld, u16* s, int wave, int lane) {
  const int per = ROWS / 4;                      // rows per wave
  const u16* gp = g + (wave * per + (lane >> 3)) * ld + (lane & 7) * 8;
  u16* sp = s + wave * per * 64;                 // wave-uniform base; lane l lands at +16B*l
#pragma unroll
  for (int ch = 0; ch < per / 8; ++ch) {
    __builtin_amdgcn_global_load_lds(
        (const __attribute__((address_space(1))) void*)(gp + ch * 8 * ld),
        (__attribute__((address_space(3))) void*)(sp + ch * 8 * 64), 16, 0, 0);
  }
}

// ---- wave computes (RT*16) x 64 outputs; block = 4 waves in 2x2 -> (RT*32) x 128 tile
template<int RT>
__device__ __forceinline__ void mfma_step(const u16* As, const u16* Bs, f32x4 (*acc)[4], int lane, int wave) {
  const int wr = (wave >> 1) * (RT * 16);
  const int wc = (wave & 1) * 64;
  const int l15 = lane & 15;
  const int lq = lane >> 4;
#pragma unroll
  for (int kk = 0; kk < 64; kk += 32) {
    bf16x8 a[RT], b[4];
#pragma unroll
    for (int i = 0; i < RT; ++i)
      a[i] = *(const bf16x8*)(As + (wr + i * 16 + l15) * 64 + kk + lq * 8);
#pragma unroll
    for (int j = 0; j < 4; ++j)
      b[j] = *(const bf16x8*)(Bs + (wc + j * 16 + l15) * 64 + kk + lq * 8);
#pragma unroll
    for (int i = 0; i < RT; ++i)
#pragma unroll
      for (int j = 0; j < 4; ++j)
        acc[i][j] = __builtin_amdgcn_mfma_f32_16x16x32_bf16(a[i], b[j], acc[i][j], 0, 0, 0);
  }
}

template<int RT>
__device__ __forceinline__ void gemm_loop(const u16* __restrict__ A, int lda,
                                          const u16* __restrict__ B, int ldb, int K,
                                          u16* As, u16* Bs, f32x4 (*acc)[4], int lane, int wave) {
  for (int k0 = 0; k0 < K; k0 += 64) {
    stage<RT * 32>(A + k0, lda, As, wave, lane);
    stage<128>(B + k0, ldb, Bs, wave, lane);
    __syncthreads();
    mfma_step<RT>(As, Bs, acc, lane, wave);
    __syncthreads();
  }
}

// ---------------- elementwise / prep kernels ----------------

__global__ __launch_bounds__(256) void k_conv(const float* __restrict__ in, u16* __restrict__ out, int n4) {
  int i = blockIdx.x * 256 + threadIdx.x;
  if (i >= n4) return;
  float4 f = ((const float4*)in)[i];
  u16x4 o = { f2bf(f.x), f2bf(f.y), f2bf(f.z), f2bf(f.w) };
  *(u16x4*)(out + i * 4) = o;
}

// x (V,N,D) f32 -> bf16 with per-v row padding to NPAD
__global__ __launch_bounds__(256) void k_convx(const float* __restrict__ x, u16* __restrict__ xb) {
  int i = blockIdx.x * 256 + threadIdx.x;     // 2,304,000 quads
  if (i >= VV * NN * DD / 4) return;
  int idx = i * 4;
  int v = idx / (NN * DD);
  int rem = idx - v * (NN * DD);
  int n = rem / DD;
  int d = rem - n * DD;
  float4 f = *(const float4*)(x + idx);
  u16x4 o = { f2bf(f.x), f2bf(f.y), f2bf(f.z), f2bf(f.w) };
  *(u16x4*)(xb + (size_t)(v * NPAD + n) * DD + d) = o;
}

// mT[v][n] padded (zeros beyond NN)
__global__ __launch_bounds__(256) void k_mt(const float* __restrict__ mask, float* __restrict__ mT) {
  int i = blockIdx.x * 256 + threadIdx.x;
  if (i >= VV * NPAD) return;
  int v = i / NPAD, n = i - v * NPAD;
  mT[i] = (n < NN) ? mask[n * VV + v] : 0.0f;
}

// q = h / max(||h||,1e-12) -> bf16; one block per (v,n) row
__global__ __launch_bounds__(256) void k_qprep(const float* __restrict__ h, u16* __restrict__ qb) {
  int b = blockIdx.x;
  int v = b / NN, n = b - v * NN;
  int t = threadIdx.x;
  float val = h[(size_t)(v * NPAD + n) * HH + t];
  float ss = val * val;
#pragma unroll
  for (int o = 32; o > 0; o >>= 1) ss += __shfl_down(ss, o, 64);
  __shared__ float red[4];
  if ((t & 63) == 0) red[t >> 6] = ss;
  __syncthreads();
  float inv = 1.0f / fmaxf(sqrtf(red[0] + red[1] + red[2] + red[3]), 1e-12f);
  qb[(size_t)(v * NPAD + n) * HH + t] = f2bf(val * inv);
}

// hmT[v][j][m] = mT[v][m]*h[v][m][j] (bf16, zero for m>=NN), 64x64 LDS transpose
__global__ __launch_bounds__(1024) void k_hmt(const float* __restrict__ h, const float* __restrict__ mT,
                                              u16* __restrict__ hmT) {
  __shared__ float t[64][65];
  int m0 = blockIdx.x * 64, j0 = blockIdx.y * 64, v = blockIdx.z;
  int tx = threadIdx.x, ty = threadIdx.y;
#pragma unroll
  for (int p = 0; p < 4; ++p) {
    int ml = ty + p * 16;
    int m = m0 + ml;
    float val = 0.0f;
    if (m < NN) val = mT[v * NPAD + m] * h[(size_t)(v * NPAD + m) * HH + j0 + tx];
    t[ml][tx] = val;
  }
  __syncthreads();
#pragma unroll
  for (int p = 0; p < 4; ++p) {
    int j = j0 + ty + p * 16;
    hmT[(size_t)(v * HH + j) * NPAD + m0 + tx] = f2bf(t[tx][ty + p * 16]);
  }
}

// S[row] = sum of bf16 A row
__global__ __launch_bounds__(64) void k_rowsum(const u16* __restrict__ Abf, float* __restrict__ S) {
  int row = blockIdx.x, lane = threadIdx.x;
  const u16* p = Abf + (size_t)row * NPAD;
  float s = 0.0f;
  for (int c = lane; c < NPAD; c += 64) s += bf2f(p[c]);
#pragma unroll
  for (int o = 32; o > 0; o >>= 1) s += __shfl_down(s, o, 64);
  if (lane == 0) S[row] = s;
}

// ---------------- GEMM kernels ----------------

// h = leaky(x @ W_in^T + b_in)   [RT=2: 64x128 tile]
__global__ __launch_bounds__(256) void k_gemm1(const u16* __restrict__ xb, const u16* __restrict__ winb,
                                               const float* __restrict__ b_in, float* __restrict__ h) {
  __shared__ u16 As[64 * 64], Bs[128 * 64];
  int lane = threadIdx.x & 63, wave = threadIdx.x >> 6;
  int col0 = blockIdx.x * 128, row0 = blockIdx.y * 64, v = blockIdx.z;
  f32x4 acc[2][4];
  f32x4 z = {0.f, 0.f, 0.f, 0.f};
  for (int i = 0; i < 2; ++i) for (int j = 0; j < 4; ++j) acc[i][j] = z;
  gemm_loop<2>(xb + (size_t)(v * NPAD + row0) * DD, DD,
               winb + (size_t)(v * HH + col0) * DD, DD, DD, As, Bs, acc, lane, wave);
  int wr = (wave >> 1) * 32, wc = (wave & 1) * 64, l15 = lane & 15, lq = lane >> 4;
#pragma unroll
  for (int i = 0; i < 2; ++i)
#pragma unroll
    for (int r = 0; r < 4; ++r) {
      int grow = row0 + wr + i * 16 + lq * 4 + r;
      if (grow < NN) {
#pragma unroll
        for (int j = 0; j < 4; ++j) {
          int gcol = col0 + wc + j * 16 + l15;
          h[(size_t)(v * NPAD + grow) * HH + gcol] = leaky(acc[i][j][r] + b_in[v * HH + gcol]);
        }
      }
    }
}

// A = max_v mask*exp(q_v q_v^T / beta), diag zeroed, bf16  [RT=4: 128x128 tile]
__global__ __launch_bounds__(256) void k_qk(const u16* __restrict__ qb, const float* __restrict__ mT,
                                            u16* __restrict__ Abf) {
  __shared__ u16 As[128 * 64], Bs[128 * 64];
  int lane = threadIdx.x & 63, wave = threadIdx.x >> 6;
  int col0 = blockIdx.x * 128, row0 = blockIdx.y * 128;
  int wr = (wave >> 1) * 64, wc = (wave & 1) * 64, l15 = lane & 15, lq = lane >> 4;
  f32x4 z = {0.f, 0.f, 0.f, 0.f};
  f32x4 rmax[4][4];
  for (int i = 0; i < 4; ++i) for (int j = 0; j < 4; ++j) rmax[i][j] = z;
  for (int v = 0; v < VV; ++v) {
    f32x4 acc[4][4];
    for (int i = 0; i < 4; ++i) for (int j = 0; j < 4; ++j) acc[i][j] = z;
    gemm_loop<4>(qb + (size_t)(v * NPAD + row0) * HH, HH,
                 qb + (size_t)(v * NPAD + col0) * HH, HH, HH, As, Bs, acc, lane, wave);
    const float* mv = mT + v * NPAD;
    float mc[4];
#pragma unroll
    for (int j = 0; j < 4; ++j) mc[j] = mv[col0 + wc + j * 16 + l15];
#pragma unroll
    for (int i = 0; i < 4; ++i)
#pragma unroll
      for (int r = 0; r < 4; ++r) {
        float mr = mv[row0 + wr + i * 16 + lq * 4 + r];
#pragma unroll
        for (int j = 0; j < 4; ++j) {
          float e = 0.0f;
          if (mr * mc[j] != 0.0f) e = __expf(acc[i][j][r] * 5.0f);
          rmax[i][j][r] = fmaxf(rmax[i][j][r], e);
        }
      }
  }
#pragma unroll
  for (int i = 0; i < 4; ++i)
#pragma unroll
    for (int r = 0; r < 4; ++r) {
      int grow = row0 + wr + i * 16 + lq * 4 + r;
#pragma unroll
      for (int j = 0; j < 4; ++j) {
        int gcol = col0 + wc + j * 16 + l15;
        float val = (grow == gcol) ? 0.0f : rmax[i][j][r];
        Abf[(size_t)grow * NPAD + gcol] = f2bf(val);
      }
    }
}

// new_x[v] = blend(A @ hmT[v] / S, h)  [RT=2]
__global__ __launch_bounds__(256) void k_pv(const u16* __restrict__ Abf, const u16* __restrict__ hmT,
                                            const float* __restrict__ h, const float* __restrict__ mT,
                                            const float* __restrict__ S,
                                            float* __restrict__ out_newx, u16* __restrict__ nxb) {
  __shared__ u16 As[64 * 64], Bs[128 * 64];
  int lane = threadIdx.x & 63, wave = threadIdx.x >> 6;
  int col0 = blockIdx.x * 128, row0 = blockIdx.y * 64, v = blockIdx.z;
  f32x4 acc[2][4];
  f32x4 z = {0.f, 0.f, 0.f, 0.f};
  for (int i = 0; i < 2; ++i) for (int j = 0; j < 4; ++j) acc[i][j] = z;
  gemm_loop<2>(Abf + (size_t)row0 * NPAD, NPAD,
               hmT + (size_t)(v * HH + col0) * NPAD, NPAD, NPAD, As, Bs, acc, lane, wave);
  int wr = (wave >> 1) * 32, wc = (wave & 1) * 64, l15 = lane & 15, lq = lane >> 4;
#pragma unroll
  for (int i = 0; i < 2; ++i)
#pragma unroll
    for (int r = 0; r < 4; ++r) {
      int grow = row0 + wr + i * 16 + lq * 4 + r;
      if (grow < NN) {
        float sc = 1.0f / (S[grow] + 1e-9f);
        float mrow = mT[v * NPAD + grow];
#pragma unroll
        for (int j = 0; j < 4; ++j) {
          int gcol = col0 + wc + j * 16 + l15;
          float val = acc[i][j][r] * sc;
          if (mrow != 0.0f) val = h[(size_t)(v * NPAD + grow) * HH + gcol];
          out_newx[(size_t)(v * NN + grow) * HH + gcol] = val;
          nxb[(size_t)(v * NPAD + grow) * HH + gcol] = f2bf(val);
        }
      }
    }
}

// x_new = leaky(new_x @ W_out^T + b_out), nan->0  [RT=2]
__global__ __launch_bounds__(256) void k_gemm3(const u16* __restrict__ nxb, const u16* __restrict__ woutb,
                                               const float* __restrict__ b_out, float* __restrict__ out_xnew) {
  __shared__ u16 As[64 * 64], Bs[128 * 64];
  int lane = threadIdx.x & 63, wave = threadIdx.x >> 6;
  int col0 = blockIdx.x * 128, row0 = blockIdx.y * 64, v = blockIdx.z;
  f32x4 acc[2][4];
  f32x4 z = {0.f, 0.f, 0.f, 0.f};
  for (int i = 0; i < 2; ++i) for (int j = 0; j < 4; ++j) acc[i][j] = z;
  gemm_loop<2>(nxb + (size_t)(v * NPAD + row0) * HH, HH,
               woutb + (size_t)(v * DD + col0) * HH, HH, HH, As, Bs, acc, lane, wave);
  int wr = (wave >> 1) * 32, wc = (wave & 1) * 64, l15 = lane & 15, lq = lane >> 4;
#pragma unroll
  for (int i = 0; i < 2; ++i)
#pragma unroll
    for (int r = 0; r < 4; ++r) {
      int grow = row0 + wr + i * 16 + lq * 4 + r;
      if (grow < NN) {
#pragma unroll
        for (int j = 0; j < 4; ++j) {
          int gcol = col0 + wc + j * 16 + l15;
          float val = leaky(acc[i][j][r] + b_out[v * DD + gcol]);
          if (val != val) val = 0.0f;
          out_xnew[(size_t)(v * NN + grow) * DD + gcol] = val;
        }
      }
    }
}

// y_n = sigmoid(y @ Wy^T + by)  [RT=2]
__global__ __launch_bounds__(256) void k_ygemm(const u16* __restrict__ yb, const u16* __restrict__ wyb,
                                               const float* __restrict__ by, float* __restrict__ out_yn) {
  __shared__ u16 As[64 * 64], Bs[128 * 64];
  int lane = threadIdx.x & 63, wave = threadIdx.x >> 6;
  int col0 = blockIdx.x * 128, row0 = blockIdx.y * 64;
  f32x4 acc[2][4];
  f32x4 z = {0.f, 0.f, 0.f, 0.f};
  for (int i = 0; i < 2; ++i) for (int j = 0; j < 4; ++j) acc[i][j] = z;
  gemm_loop<2>(yb + (size_t)row0 * DYY, DYY, wyb + (size_t)col0 * DYY, DYY, DYY, As, Bs, acc, lane, wave);
  int wr = (wave >> 1) * 32, wc = (wave & 1) * 64, l15 = lane & 15, lq = lane >> 4;
#pragma unroll
  for (int i = 0; i < 2; ++i)
#pragma unroll
    for (int r = 0; r < 4; ++r) {
      int grow = row0 + wr + i * 16 + lq * 4 + r;
      if (grow < NN) {
#pragma unroll
        for (int j = 0; j < 4; ++j) {
          int gcol = col0 + wc + j * 16 + l15;
          float val = acc[i][j][r] + by[gcol];
          out_yn[(size_t)grow * HH + gcol] = 1.0f / (1.0f + __expf(-val));
        }
      }
    }
}

// ---------------- launch ----------------

extern "C" void kernel_launch(void* const* d_in, const int* in_sizes, int n_in,
                              void* d_out, int out_size, void* d_ws, size_t ws_size,
                              hipStream_t stream) {
  const float* x    = (const float*)d_in[0];
  const float* y    = (const float*)d_in[1];
  const float* mask = (const float*)d_in[2];
  const float* W_in = (const float*)d_in[3];
  const float* b_in = (const float*)d_in[4];
  const float* W_out= (const float*)d_in[5];
  const float* b_out= (const float*)d_in[6];
  const float* Wy   = (const float*)d_in[7];
  const float* by   = (const float*)d_in[8];

  float* out_newx = (float*)d_out;
  float* out_xnew = out_newx + (size_t)VV * NN * HH;
  float* out_yn   = out_xnew + (size_t)VV * NN * DD;

  char* w = (char*)d_ws;
  size_t off = 0;
  auto alloc = [&](size_t bytes) -> void* {
    void* p = w + off;
    off += (bytes + 255) & ~(size_t)255;
    return p;
  };
  u16*   xb    = (u16*)alloc((size_t)VV * NPAD * DD * 2);
  u16*   yb    = (u16*)alloc((size_t)NPAD * DYY * 2);
  u16*   winb  = (u16*)alloc((size_t)VV * HH * DD * 2);
  u16*   woutb = (u16*)alloc((size_t)VV * DD * HH * 2);
  u16*   wyb   = (u16*)alloc((size_t)HH * DYY * 2);
  float* h     = (float*)alloc((size_t)VV * NPAD * HH * 4);
  u16*   qb    = (u16*)alloc((size_t)VV * NPAD * HH * 2);
  u16*   hmT   = (u16*)alloc((size_t)VV * HH * NPAD * 2);
  u16*   nxb   = (u16*)alloc((size_t)VV * NPAD * HH * 2);
  float* mT    = (float*)alloc((size_t)VV * NPAD * 4);
  float* S     = (float*)alloc((size_t)NPAD * 4);
  u16*   Abf   = (u16*)alloc((size_t)NPAD * NPAD * 2);
  (void)ws_size; (void)in_sizes; (void)n_in; (void)out_size;

  // conversions
  k_conv<<<384, 256, 0, stream>>>(W_in, winb, VV * HH * DD / 4);
  k_conv<<<384, 256, 0, stream>>>(W_out, woutb, VV * DD * HH / 4);
  k_conv<<<128, 256, 0, stream>>>(Wy, wyb, HH * DYY / 4);
  k_conv<<<3000, 256, 0, stream>>>(y, yb, NN * DYY / 4);
  k_convx<<<9000, 256, 0, stream>>>(x, xb);
  k_mt<<<(VV * NPAD + 255) / 256, 256, 0, stream>>>(mask, mT);

  // h, q, hmT
  k_gemm1<<<dim3(2, 94, 3), 256, 0, stream>>>(xb, winb, b_in, h);
  k_qprep<<<VV * NN, 256, 0, stream>>>(h, qb);
  k_hmt<<<dim3(94, 4, 3), dim3(64, 16), 0, stream>>>(h, mT, hmT);

  // attention
  k_qk<<<dim3(47, 47), 256, 0, stream>>>(qb, mT, Abf);
  k_rowsum<<<NN, 64, 0, stream>>>(Abf, S);
  k_pv<<<dim3(2, 94, 3), 256, 0, stream>>>(Abf, hmT, h, mT, S, out_newx, nxb);

  // outputs
  k_gemm3<<<dim3(4, 94, 3), 256, 0, stream>>>(nxb, woutb, b_out, out_xnew);
  k_ygemm<<<dim3(2, 94), 256, 0, stream>>>(yb, wyb, by, out_yn);
}

// Round 2
// 468.868 us; speedup vs baseline: 1.1098x; 1.1098x over previous
//
#include <hip/hip_runtime.h>

#define VV 3
#define NN 6000
#define DD 512
#define HH 256
#define DYY 512
#define NPAD 6016   // 47*128

typedef unsigned short u16;
typedef __bf16 bf16x8 __attribute__((ext_vector_type(8)));
typedef float f32x4 __attribute__((ext_vector_type(4)));
typedef u16 u16x4 __attribute__((ext_vector_type(4)));

__device__ __forceinline__ u16 f2bf(float f) {
  unsigned int b = __builtin_bit_cast(unsigned int, f);
  b += 0x7FFFu + ((b >> 16) & 1u);
  return (u16)(b >> 16);
}
__device__ __forceinline__ float bf2f(u16 u) {
  unsigned int b = ((unsigned int)u) << 16;
  return __builtin_bit_cast(float, b);
}
__device__ __forceinline__ float leaky(float v) { return v >= 0.0f ? v : 0.1f * v; }

// ---- stage ROWS x 64 bf16 tile: global row-major (ld elems) -> LDS [ROWS][64], via global_load_lds width=16
template<int ROWS>
__device__ __forceinline__ void stage(const u16* __restrict__ g, int ld, u16* s, int wave, int lane) {
  const int per = ROWS / 4;                      // rows per wave
  const u16* gp = g + (wave * per + (lane >> 3)) * ld + (lane & 7) * 8;
  u16* sp = s + wave * per * 64;                 // wave-uniform base; lane l lands at +16B*l
#pragma unroll
  for (int ch = 0; ch < per / 8; ++ch) {
    __builtin_amdgcn_global_load_lds(
        (const __attribute__((address_space(1))) void*)(gp + ch * 8 * ld),
        (__attribute__((address_space(3))) void*)(sp + ch * 8 * 64), 16, 0, 0);
  }
}

// ---- wave computes (RT*16) x 64 outputs; block = 4 waves in 2x2 -> (RT*32) x 128 tile
template<int RT>
__device__ __forceinline__ void mfma_step(const u16* As, const u16* Bs, f32x4 (*acc)[4], int lane, int wave) {
  const int wr = (wave >> 1) * (RT * 16);
  const int wc = (wave & 1) * 64;
  const int l15 = lane & 15;
  const int lq = lane >> 4;
#pragma unroll
  for (int kk = 0; kk < 64; kk += 32) {
    bf16x8 a[RT], b[4];
#pragma unroll
    for (int i = 0; i < RT; ++i)
      a[i] = *(const bf16x8*)(As + (wr + i * 16 + l15) * 64 + kk + lq * 8);
#pragma unroll
    for (int j = 0; j < 4; ++j)
      b[j] = *(const bf16x8*)(Bs + (wc + j * 16 + l15) * 64 + kk + lq * 8);
#pragma unroll
    for (int i = 0; i < RT; ++i)
#pragma unroll
      for (int j = 0; j < 4; ++j)
        acc[i][j] = __builtin_amdgcn_mfma_f32_16x16x32_bf16(a[i], b[j], acc[i][j], 0, 0, 0);
  }
}

template<int RT>
__device__ __forceinline__ void gemm_loop(const u16* __restrict__ A, int lda,
                                          const u16* __restrict__ B, int ldb, int K,
                                          u16* As, u16* Bs, f32x4 (*acc)[4], int lane, int wave) {
  for (int k0 = 0; k0 < K; k0 += 64) {
    stage<RT * 32>(A + k0, lda, As, wave, lane);
    stage<128>(B + k0, ldb, Bs, wave, lane);
    __syncthreads();
    mfma_step<RT>(As, Bs, acc, lane, wave);
    __syncthreads();
  }
}

// ---------------- elementwise / prep kernels ----------------

__global__ __launch_bounds__(256) void k_conv(const float* __restrict__ in, u16* __restrict__ out, int n4) {
  int i = blockIdx.x * 256 + threadIdx.x;
  if (i >= n4) return;
  float4 f = ((const float4*)in)[i];
  u16x4 o = { f2bf(f.x), f2bf(f.y), f2bf(f.z), f2bf(f.w) };
  *(u16x4*)(out + i * 4) = o;
}

// x (V,N,D) f32 -> bf16 with per-v row padding to NPAD
__global__ __launch_bounds__(256) void k_convx(const float* __restrict__ x, u16* __restrict__ xb) {
  int i = blockIdx.x * 256 + threadIdx.x;     // 2,304,000 quads
  if (i >= VV * NN * DD / 4) return;
  int idx = i * 4;
  int v = idx / (NN * DD);
  int rem = idx - v * (NN * DD);
  int n = rem / DD;
  int d = rem - n * DD;
  float4 f = *(const float4*)(x + idx);
  u16x4 o = { f2bf(f.x), f2bf(f.y), f2bf(f.z), f2bf(f.w) };
  *(u16x4*)(xb + (size_t)(v * NPAD + n) * DD + d) = o;
}

// mT[v][n] padded (zeros beyond NN)
__global__ __launch_bounds__(256) void k_mt(const float* __restrict__ mask, float* __restrict__ mT) {
  int i = blockIdx.x * 256 + threadIdx.x;
  if (i >= VV * NPAD) return;
  int v = i / NPAD, n = i - v * NPAD;
  mT[i] = (n < NN) ? mask[n * VV + v] : 0.0f;
}

// q = h / max(||h||,1e-12) -> bf16; one block per (v,n) row
__global__ __launch_bounds__(256) void k_qprep(const float* __restrict__ h, u16* __restrict__ qb) {
  int b = blockIdx.x;
  int v = b / NN, n = b - v * NN;
  int t = threadIdx.x;
  float val = h[(size_t)(v * NPAD + n) * HH + t];
  float ss = val * val;
#pragma unroll
  for (int o = 32; o > 0; o >>= 1) ss += __shfl_down(ss, o, 64);
  __shared__ float red[4];
  if ((t & 63) == 0) red[t >> 6] = ss;
  __syncthreads();
  float inv = 1.0f / fmaxf(sqrtf(red[0] + red[1] + red[2] + red[3]), 1e-12f);
  qb[(size_t)(v * NPAD + n) * HH + t] = f2bf(val * inv);
}

// hmT[v][j][m] = mT[v][m]*h[v][m][j] (bf16, zero for m>=NN), 64x64 LDS transpose
__global__ __launch_bounds__(1024) void k_hmt(const float* __restrict__ h, const float* __restrict__ mT,
                                              u16* __restrict__ hmT) {
  __shared__ float t[64][65];
  int m0 = blockIdx.x * 64, j0 = blockIdx.y * 64, v = blockIdx.z;
  int tx = threadIdx.x, ty = threadIdx.y;
#pragma unroll
  for (int p = 0; p < 4; ++p) {
    int ml = ty + p * 16;
    int m = m0 + ml;
    float val = 0.0f;
    if (m < NN) val = mT[v * NPAD + m] * h[(size_t)(v * NPAD + m) * HH + j0 + tx];
    t[ml][tx] = val;
  }
  __syncthreads();
#pragma unroll
  for (int p = 0; p < 4; ++p) {
    int j = j0 + ty + p * 16;
    hmT[(size_t)(v * HH + j) * NPAD + m0 + tx] = f2bf(t[tx][ty + p * 16]);
  }
}

// S[row] = sum of bf16 A row (vectorized: 256 threads x bf16x8)
__global__ __launch_bounds__(256) void k_rowsum(const u16* __restrict__ Abf, float* __restrict__ S) {
  int row = blockIdx.x, t = threadIdx.x;
  const u16* p = Abf + (size_t)row * NPAD;
  float s = 0.0f;
  for (int c = t * 8; c < NPAD; c += 256 * 8) {
    bf16x8 v = *(const bf16x8*)(p + c);
#pragma unroll
    for (int k = 0; k < 8; ++k) s += (float)v[k];
  }
#pragma unroll
  for (int o = 32; o > 0; o >>= 1) s += __shfl_down(s, o, 64);
  __shared__ float red[4];
  if ((t & 63) == 0) red[t >> 6] = s;
  __syncthreads();
  if (t == 0) S[row] = red[0] + red[1] + red[2] + red[3];
}

// ---------------- GEMM kernels ----------------

// h = leaky(x @ W_in^T + b_in)   [RT=2: 64x128 tile]
__global__ __launch_bounds__(256) void k_gemm1(const u16* __restrict__ xb, const u16* __restrict__ winb,
                                               const float* __restrict__ b_in, float* __restrict__ h) {
  __shared__ u16 As[64 * 64], Bs[128 * 64];
  int lane = threadIdx.x & 63, wave = threadIdx.x >> 6;
  int col0 = blockIdx.x * 128, row0 = blockIdx.y * 64, v = blockIdx.z;
  f32x4 acc[2][4];
  f32x4 z = {0.f, 0.f, 0.f, 0.f};
  for (int i = 0; i < 2; ++i) for (int j = 0; j < 4; ++j) acc[i][j] = z;
  gemm_loop<2>(xb + (size_t)(v * NPAD + row0) * DD, DD,
               winb + (size_t)(v * HH + col0) * DD, DD, DD, As, Bs, acc, lane, wave);
  int wr = (wave >> 1) * 32, wc = (wave & 1) * 64, l15 = lane & 15, lq = lane >> 4;
#pragma unroll
  for (int i = 0; i < 2; ++i)
#pragma unroll
    for (int r = 0; r < 4; ++r) {
      int grow = row0 + wr + i * 16 + lq * 4 + r;
      if (grow < NN) {
#pragma unroll
        for (int j = 0; j < 4; ++j) {
          int gcol = col0 + wc + j * 16 + l15;
          h[(size_t)(v * NPAD + grow) * HH + gcol] = leaky(acc[i][j][r] + b_in[v * HH + gcol]);
        }
      }
    }
}

// A = max_v mask*exp(q_v q_v^T / beta), diag zeroed, bf16
// v fused into K-loop: 3 accumulators, all-v LDS staging, 64x128 block tile
__global__ __launch_bounds__(256) void k_qk(const u16* __restrict__ qb, const float* __restrict__ mT,
                                            u16* __restrict__ Abf) {
  __shared__ u16 As[VV][64 * 64];    // 24 KB
  __shared__ u16 Bs[VV][128 * 64];   // 48 KB
  int lane = threadIdx.x & 63, wave = threadIdx.x >> 6;
  int col0 = blockIdx.x * 128, row0 = blockIdx.y * 64;
  f32x4 z = {0.f, 0.f, 0.f, 0.f};
  f32x4 acc[VV][2][4];
  for (int v = 0; v < VV; ++v)
    for (int i = 0; i < 2; ++i)
      for (int j = 0; j < 4; ++j) acc[v][i][j] = z;
  for (int k0 = 0; k0 < HH; k0 += 64) {
#pragma unroll
    for (int v = 0; v < VV; ++v) {
      stage<64>(qb + (size_t)(v * NPAD + row0) * HH + k0, HH, As[v], wave, lane);
      stage<128>(qb + (size_t)(v * NPAD + col0) * HH + k0, HH, Bs[v], wave, lane);
    }
    __syncthreads();
#pragma unroll
    for (int v = 0; v < VV; ++v)
      mfma_step<2>(As[v], Bs[v], acc[v], lane, wave);
    __syncthreads();
  }
  int wr = (wave >> 1) * 32, wc = (wave & 1) * 64, l15 = lane & 15, lq = lane >> 4;
  float mc[VV][4];
#pragma unroll
  for (int v = 0; v < VV; ++v)
#pragma unroll
    for (int j = 0; j < 4; ++j) mc[v][j] = mT[v * NPAD + col0 + wc + j * 16 + l15];
#pragma unroll
  for (int i = 0; i < 2; ++i)
#pragma unroll
    for (int r = 0; r < 4; ++r) {
      int grow = row0 + wr + i * 16 + lq * 4 + r;
      float mr0 = mT[grow];
      float mr1 = mT[NPAD + grow];
      float mr2 = mT[2 * NPAD + grow];
#pragma unroll
      for (int j = 0; j < 4; ++j) {
        int gcol = col0 + wc + j * 16 + l15;
        float e0 = (mr0 * mc[0][j] != 0.0f) ? __expf(acc[0][i][j][r] * 5.0f) : 0.0f;
        float e1 = (mr1 * mc[1][j] != 0.0f) ? __expf(acc[1][i][j][r] * 5.0f) : 0.0f;
        float e2 = (mr2 * mc[2][j] != 0.0f) ? __expf(acc[2][i][j][r] * 5.0f) : 0.0f;
        float val = fmaxf(fmaxf(e0, e1), e2);
        if (grow == gcol) val = 0.0f;
        Abf[(size_t)grow * NPAD + gcol] = f2bf(val);
      }
    }
}

// new_x[v] = blend(A @ hmT[v] / S, h)  [RT=2]
__global__ __launch_bounds__(256) void k_pv(const u16* __restrict__ Abf, const u16* __restrict__ hmT,
                                            const float* __restrict__ h, const float* __restrict__ mT,
                                            const float* __restrict__ S,
                                            float* __restrict__ out_newx, u16* __restrict__ nxb) {
  __shared__ u16 As[64 * 64], Bs[128 * 64];
  int lane = threadIdx.x & 63, wave = threadIdx.x >> 6;
  int col0 = blockIdx.x * 128, row0 = blockIdx.y * 64, v = blockIdx.z;
  f32x4 acc[2][4];
  f32x4 z = {0.f, 0.f, 0.f, 0.f};
  for (int i = 0; i < 2; ++i) for (int j = 0; j < 4; ++j) acc[i][j] = z;
  gemm_loop<2>(Abf + (size_t)row0 * NPAD, NPAD,
               hmT + (size_t)(v * HH + col0) * NPAD, NPAD, NPAD, As, Bs, acc, lane, wave);
  int wr = (wave >> 1) * 32, wc = (wave & 1) * 64, l15 = lane & 15, lq = lane >> 4;
#pragma unroll
  for (int i = 0; i < 2; ++i)
#pragma unroll
    for (int r = 0; r < 4; ++r) {
      int grow = row0 + wr + i * 16 + lq * 4 + r;
      if (grow < NN) {
        float sc = 1.0f / (S[grow] + 1e-9f);
        float mrow = mT[v * NPAD + grow];
#pragma unroll
        for (int j = 0; j < 4; ++j) {
          int gcol = col0 + wc + j * 16 + l15;
          float val = acc[i][j][r] * sc;
          if (mrow != 0.0f) val = h[(size_t)(v * NPAD + grow) * HH + gcol];
          out_newx[(size_t)(v * NN + grow) * HH + gcol] = val;
          nxb[(size_t)(v * NPAD + grow) * HH + gcol] = f2bf(val);
        }
      }
    }
}

// x_new = leaky(new_x @ W_out^T + b_out), nan->0  [RT=2]
__global__ __launch_bounds__(256) void k_gemm3(const u16* __restrict__ nxb, const u16* __restrict__ woutb,
                                               const float* __restrict__ b_out, float* __restrict__ out_xnew) {
  __shared__ u16 As[64 * 64], Bs[128 * 64];
  int lane = threadIdx.x & 63, wave = threadIdx.x >> 6;
  int col0 = blockIdx.x * 128, row0 = blockIdx.y * 64, v = blockIdx.z;
  f32x4 acc[2][4];
  f32x4 z = {0.f, 0.f, 0.f, 0.f};
  for (int i = 0; i < 2; ++i) for (int j = 0; j < 4; ++j) acc[i][j] = z;
  gemm_loop<2>(nxb + (size_t)(v * NPAD + row0) * HH, HH,
               woutb + (size_t)(v * DD + col0) * HH, HH, HH, As, Bs, acc, lane, wave);
  int wr = (wave >> 1) * 32, wc = (wave & 1) * 64, l15 = lane & 15, lq = lane >> 4;
#pragma unroll
  for (int i = 0; i < 2; ++i)
#pragma unroll
    for (int r = 0; r < 4; ++r) {
      int grow = row0 + wr + i * 16 + lq * 4 + r;
      if (grow < NN) {
#pragma unroll
        for (int j = 0; j < 4; ++j) {
          int gcol = col0 + wc + j * 16 + l15;
          float val = leaky(acc[i][j][r] + b_out[v * DD + gcol]);
          if (val != val) val = 0.0f;
          out_xnew[(size_t)(v * NN + grow) * DD + gcol] = val;
        }
      }
    }
}

// y_n = sigmoid(y @ Wy^T + by)  [RT=2]
__global__ __launch_bounds__(256) void k_ygemm(const u16* __restrict__ yb, const u16* __restrict__ wyb,
                                               const float* __restrict__ by, float* __restrict__ out_yn) {
  __shared__ u16 As[64 * 64], Bs[128 * 64];
  int lane = threadIdx.x & 63, wave = threadIdx.x >> 6;
  int col0 = blockIdx.x * 128, row0 = blockIdx.y * 64;
  f32x4 acc[2][4];
  f32x4 z = {0.f, 0.f, 0.f, 0.f};
  for (int i = 0; i < 2; ++i) for (int j = 0; j < 4; ++j) acc[i][j] = z;
  gemm_loop<2>(yb + (size_t)row0 * DYY, DYY, wyb + (size_t)col0 * DYY, DYY, DYY, As, Bs, acc, lane, wave);
  int wr = (wave >> 1) * 32, wc = (wave & 1) * 64, l15 = lane & 15, lq = lane >> 4;
#pragma unroll
  for (int i = 0; i < 2; ++i)
#pragma unroll
    for (int r = 0; r < 4; ++r) {
      int grow = row0 + wr + i * 16 + lq * 4 + r;
      if (grow < NN) {
#pragma unroll
        for (int j = 0; j < 4; ++j) {
          int gcol = col0 + wc + j * 16 + l15;
          float val = acc[i][j][r] + by[gcol];
          out_yn[(size_t)grow * HH + gcol] = 1.0f / (1.0f + __expf(-val));
        }
      }
    }
}

// ---------------- launch ----------------

extern "C" void kernel_launch(void* const* d_in, const int* in_sizes, int n_in,
                              void* d_out, int out_size, void* d_ws, size_t ws_size,
                              hipStream_t stream) {
  const float* x    = (const float*)d_in[0];
  const float* y    = (const float*)d_in[1];
  const float* mask = (const float*)d_in[2];
  const float* W_in = (const float*)d_in[3];
  const float* b_in = (const float*)d_in[4];
  const float* W_out= (const float*)d_in[5];
  const float* b_out= (const float*)d_in[6];
  const float* Wy   = (const float*)d_in[7];
  const float* by   = (const float*)d_in[8];

  float* out_newx = (float*)d_out;
  float* out_xnew = out_newx + (size_t)VV * NN * HH;
  float* out_yn   = out_xnew + (size_t)VV * NN * DD;

  char* w = (char*)d_ws;
  size_t off = 0;
  auto alloc = [&](size_t bytes) -> void* {
    void* p = w + off;
    off += (bytes + 255) & ~(size_t)255;
    return p;
  };
  u16*   xb    = (u16*)alloc((size_t)VV * NPAD * DD * 2);
  u16*   yb    = (u16*)alloc((size_t)NPAD * DYY * 2);
  u16*   winb  = (u16*)alloc((size_t)VV * HH * DD * 2);
  u16*   woutb = (u16*)alloc((size_t)VV * DD * HH * 2);
  u16*   wyb   = (u16*)alloc((size_t)HH * DYY * 2);
  float* h     = (float*)alloc((size_t)VV * NPAD * HH * 4);
  u16*   qb    = (u16*)alloc((size_t)VV * NPAD * HH * 2);
  u16*   hmT   = (u16*)alloc((size_t)VV * HH * NPAD * 2);
  u16*   nxb   = (u16*)alloc((size_t)VV * NPAD * HH * 2);
  float* mT    = (float*)alloc((size_t)VV * NPAD * 4);
  float* S     = (float*)alloc((size_t)NPAD * 4);
  u16*   Abf   = (u16*)alloc((size_t)NPAD * NPAD * 2);
  (void)ws_size; (void)in_sizes; (void)n_in; (void)out_size;

  // conversions
  k_conv<<<384, 256, 0, stream>>>(W_in, winb, VV * HH * DD / 4);
  k_conv<<<384, 256, 0, stream>>>(W_out, woutb, VV * DD * HH / 4);
  k_conv<<<128, 256, 0, stream>>>(Wy, wyb, HH * DYY / 4);
  k_conv<<<3000, 256, 0, stream>>>(y, yb, NN * DYY / 4);
  k_convx<<<9000, 256, 0, stream>>>(x, xb);
  k_mt<<<(VV * NPAD + 255) / 256, 256, 0, stream>>>(mask, mT);

  // h, q, hmT
  k_gemm1<<<dim3(2, 94, 3), 256, 0, stream>>>(xb, winb, b_in, h);
  k_qprep<<<VV * NN, 256, 0, stream>>>(h, qb);
  k_hmt<<<dim3(94, 4, 3), dim3(64, 16), 0, stream>>>(h, mT, hmT);

  // attention
  k_qk<<<dim3(47, 94), 256, 0, stream>>>(qb, mT, Abf);
  k_rowsum<<<NN, 256, 0, stream>>>(Abf, S);
  k_pv<<<dim3(2, 94, 3), 256, 0, stream>>>(Abf, hmT, h, mT, S, out_newx, nxb);

  // outputs
  k_gemm3<<<dim3(4, 94, 3), 256, 0, stream>>>(nxb, woutb, b_out, out_xnew);
  k_ygemm<<<dim3(2, 94), 256, 0, stream>>>(yb, wyb, by, out_yn);
}

// Round 3
// 463.060 us; speedup vs baseline: 1.1237x; 1.0125x over previous
//
#include <hip/hip_runtime.h>

#define VV 3
#define NN 6000
#define DD 512
#define HH 256
#define DYY 512
#define NPAD 6016   // 47*128

typedef unsigned short u16;
typedef __bf16 bf16x8 __attribute__((ext_vector_type(8)));
typedef float f32x4 __attribute__((ext_vector_type(4)));
typedef u16 u16x4 __attribute__((ext_vector_type(4)));

__device__ __forceinline__ u16 f2bf(float f) {
  unsigned int b = __builtin_bit_cast(unsigned int, f);
  b += 0x7FFFu + ((b >> 16) & 1u);
  return (u16)(b >> 16);
}
__device__ __forceinline__ float bf2f(u16 u) {
  unsigned int b = ((unsigned int)u) << 16;
  return __builtin_bit_cast(float, b);
}
__device__ __forceinline__ float leaky(float v) { return v >= 0.0f ? v : 0.1f * v; }

// ---- stage ROWS x 64 bf16 tile: global row-major (ld elems) -> LDS [ROWS][64], via global_load_lds width=16
template<int ROWS>
__device__ __forceinline__ void stage(const u16* __restrict__ g, int ld, u16* s, int wave, int lane) {
  const int per = ROWS / 4;                      // rows per wave
  const u16* gp = g + (wave * per + (lane >> 3)) * ld + (lane & 7) * 8;
  u16* sp = s + wave * per * 64;                 // wave-uniform base; lane l lands at +16B*l
#pragma unroll
  for (int ch = 0; ch < per / 8; ++ch) {
    __builtin_amdgcn_global_load_lds(
        (const __attribute__((address_space(1))) void*)(gp + ch * 8 * ld),
        (__attribute__((address_space(3))) void*)(sp + ch * 8 * 64), 16, 0, 0);
  }
}

// ---- wave computes (RT*16) x 64 outputs; block = 4 waves in 2x2 -> (RT*32) x 128 tile
template<int RT>
__device__ __forceinline__ void mfma_step(const u16* As, const u16* Bs, f32x4 (*acc)[4], int lane, int wave) {
  const int wr = (wave >> 1) * (RT * 16);
  const int wc = (wave & 1) * 64;
  const int l15 = lane & 15;
  const int lq = lane >> 4;
#pragma unroll
  for (int kk = 0; kk < 64; kk += 32) {
    bf16x8 a[RT], b[4];
#pragma unroll
    for (int i = 0; i < RT; ++i)
      a[i] = *(const bf16x8*)(As + (wr + i * 16 + l15) * 64 + kk + lq * 8);
#pragma unroll
    for (int j = 0; j < 4; ++j)
      b[j] = *(const bf16x8*)(Bs + (wc + j * 16 + l15) * 64 + kk + lq * 8);
#pragma unroll
    for (int i = 0; i < RT; ++i)
#pragma unroll
      for (int j = 0; j < 4; ++j)
        acc[i][j] = __builtin_amdgcn_mfma_f32_16x16x32_bf16(a[i], b[j], acc[i][j], 0, 0, 0);
  }
}

template<int RT>
__device__ __forceinline__ void gemm_loop(const u16* __restrict__ A, int lda,
                                          const u16* __restrict__ B, int ldb, int K,
                                          u16* As, u16* Bs, f32x4 (*acc)[4], int lane, int wave) {
  for (int k0 = 0; k0 < K; k0 += 64) {
    stage<RT * 32>(A + k0, lda, As, wave, lane);
    stage<128>(B + k0, ldb, Bs, wave, lane);
    __syncthreads();
    mfma_step<RT>(As, Bs, acc, lane, wave);
    __syncthreads();
  }
}

// ---------------- elementwise / prep kernels ----------------

__global__ __launch_bounds__(256) void k_conv(const float* __restrict__ in, u16* __restrict__ out, int n4) {
  int i = blockIdx.x * 256 + threadIdx.x;
  if (i >= n4) return;
  float4 f = ((const float4*)in)[i];
  u16x4 o = { f2bf(f.x), f2bf(f.y), f2bf(f.z), f2bf(f.w) };
  *(u16x4*)(out + i * 4) = o;
}

// x (V,N,D) f32 -> bf16 with per-v row padding to NPAD
__global__ __launch_bounds__(256) void k_convx(const float* __restrict__ x, u16* __restrict__ xb) {
  int i = blockIdx.x * 256 + threadIdx.x;     // 2,304,000 quads
  if (i >= VV * NN * DD / 4) return;
  int idx = i * 4;
  int v = idx / (NN * DD);
  int rem = idx - v * (NN * DD);
  int n = rem / DD;
  int d = rem - n * DD;
  float4 f = *(const float4*)(x + idx);
  u16x4 o = { f2bf(f.x), f2bf(f.y), f2bf(f.z), f2bf(f.w) };
  *(u16x4*)(xb + (size_t)(v * NPAD + n) * DD + d) = o;
}

// mT[v][n] padded (zeros beyond NN)
__global__ __launch_bounds__(256) void k_mt(const float* __restrict__ mask, float* __restrict__ mT) {
  int i = blockIdx.x * 256 + threadIdx.x;
  if (i >= VV * NPAD) return;
  int v = i / NPAD, n = i - v * NPAD;
  mT[i] = (n < NN) ? mask[n * VV + v] : 0.0f;
}

// q = h / max(||h||,1e-12) -> bf16; one block per (v,n) row
__global__ __launch_bounds__(256) void k_qprep(const float* __restrict__ h, u16* __restrict__ qb) {
  int b = blockIdx.x;
  int v = b / NN, n = b - v * NN;
  int t = threadIdx.x;
  float val = h[(size_t)(v * NPAD + n) * HH + t];
  float ss = val * val;
#pragma unroll
  for (int o = 32; o > 0; o >>= 1) ss += __shfl_down(ss, o, 64);
  __shared__ float red[4];
  if ((t & 63) == 0) red[t >> 6] = ss;
  __syncthreads();
  float inv = 1.0f / fmaxf(sqrtf(red[0] + red[1] + red[2] + red[3]), 1e-12f);
  qb[(size_t)(v * NPAD + n) * HH + t] = f2bf(val * inv);
}

// hmT[v][j][m] = mT[v][m]*h[v][m][j] (bf16, zero for m>=NN), 64x64 LDS transpose
__global__ __launch_bounds__(1024) void k_hmt(const float* __restrict__ h, const float* __restrict__ mT,
                                              u16* __restrict__ hmT) {
  __shared__ float t[64][65];
  int m0 = blockIdx.x * 64, j0 = blockIdx.y * 64, v = blockIdx.z;
  int tx = threadIdx.x, ty = threadIdx.y;
#pragma unroll
  for (int p = 0; p < 4; ++p) {
    int ml = ty + p * 16;
    int m = m0 + ml;
    float val = 0.0f;
    if (m < NN) val = mT[v * NPAD + m] * h[(size_t)(v * NPAD + m) * HH + j0 + tx];
    t[ml][tx] = val;
  }
  __syncthreads();
#pragma unroll
  for (int p = 0; p < 4; ++p) {
    int j = j0 + ty + p * 16;
    hmT[(size_t)(v * HH + j) * NPAD + m0 + tx] = f2bf(t[tx][ty + p * 16]);
  }
}

// ---------------- GEMM kernels ----------------

// h = leaky(x @ W_in^T + b_in)   [RT=2: 64x128 tile]
__global__ __launch_bounds__(256) void k_gemm1(const u16* __restrict__ xb, const u16* __restrict__ winb,
                                               const float* __restrict__ b_in, float* __restrict__ h) {
  __shared__ u16 As[64 * 64], Bs[128 * 64];
  int lane = threadIdx.x & 63, wave = threadIdx.x >> 6;
  int col0 = blockIdx.x * 128, row0 = blockIdx.y * 64, v = blockIdx.z;
  f32x4 acc[2][4];
  f32x4 z = {0.f, 0.f, 0.f, 0.f};
  for (int i = 0; i < 2; ++i) for (int j = 0; j < 4; ++j) acc[i][j] = z;
  gemm_loop<2>(xb + (size_t)(v * NPAD + row0) * DD, DD,
               winb + (size_t)(v * HH + col0) * DD, DD, DD, As, Bs, acc, lane, wave);
  int wr = (wave >> 1) * 32, wc = (wave & 1) * 64, l15 = lane & 15, lq = lane >> 4;
#pragma unroll
  for (int i = 0; i < 2; ++i)
#pragma unroll
    for (int r = 0; r < 4; ++r) {
      int grow = row0 + wr + i * 16 + lq * 4 + r;
      if (grow < NN) {
#pragma unroll
        for (int j = 0; j < 4; ++j) {
          int gcol = col0 + wc + j * 16 + l15;
          h[(size_t)(v * NPAD + grow) * HH + gcol] = leaky(acc[i][j][r] + b_in[v * HH + gcol]);
        }
      }
    }
}

// A = max_v mask*exp(q_v q_v^T / beta), diag zeroed, bf16; also accumulates row sums into S
// v fused into K-loop: 3 accumulators, all-v LDS staging, 64x128 block tile
__global__ __launch_bounds__(256) void k_qk(const u16* __restrict__ qb, const float* __restrict__ mT,
                                            u16* __restrict__ Abf, float* __restrict__ S) {
  __shared__ u16 As[VV][64 * 64];    // 24 KB
  __shared__ u16 Bs[VV][128 * 64];   // 48 KB
  int lane = threadIdx.x & 63, wave = threadIdx.x >> 6;
  int col0 = blockIdx.x * 128, row0 = blockIdx.y * 64;
  f32x4 z = {0.f, 0.f, 0.f, 0.f};
  f32x4 acc[VV][2][4];
  for (int v = 0; v < VV; ++v)
    for (int i = 0; i < 2; ++i)
      for (int j = 0; j < 4; ++j) acc[v][i][j] = z;
  for (int k0 = 0; k0 < HH; k0 += 64) {
#pragma unroll
    for (int v = 0; v < VV; ++v) {
      stage<64>(qb + (size_t)(v * NPAD + row0) * HH + k0, HH, As[v], wave, lane);
      stage<128>(qb + (size_t)(v * NPAD + col0) * HH + k0, HH, Bs[v], wave, lane);
    }
    __syncthreads();
#pragma unroll
    for (int v = 0; v < VV; ++v)
      mfma_step<2>(As[v], Bs[v], acc[v], lane, wave);
    __syncthreads();
  }
  int wr = (wave >> 1) * 32, wc = (wave & 1) * 64, l15 = lane & 15, lq = lane >> 4;
  float mc[VV][4];
#pragma unroll
  for (int v = 0; v < VV; ++v)
#pragma unroll
    for (int j = 0; j < 4; ++j) mc[v][j] = mT[v * NPAD + col0 + wc + j * 16 + l15];
#pragma unroll
  for (int i = 0; i < 2; ++i)
#pragma unroll
    for (int r = 0; r < 4; ++r) {
      int grow = row0 + wr + i * 16 + lq * 4 + r;
      float mr0 = mT[grow];
      float mr1 = mT[NPAD + grow];
      float mr2 = mT[2 * NPAD + grow];
      float rs = 0.0f;
#pragma unroll
      for (int j = 0; j < 4; ++j) {
        int gcol = col0 + wc + j * 16 + l15;
        float e0 = (mr0 * mc[0][j] != 0.0f) ? __expf(acc[0][i][j][r] * 5.0f) : 0.0f;
        float e1 = (mr1 * mc[1][j] != 0.0f) ? __expf(acc[1][i][j][r] * 5.0f) : 0.0f;
        float e2 = (mr2 * mc[2][j] != 0.0f) ? __expf(acc[2][i][j][r] * 5.0f) : 0.0f;
        float val = fmaxf(fmaxf(e0, e1), e2);
        if (grow == gcol) val = 0.0f;
        rs += val;
        Abf[(size_t)grow * NPAD + gcol] = f2bf(val);
      }
      // reduce rs across the 16 l15-lanes (they share grow), one atomic per row
#pragma unroll
      for (int m = 1; m < 16; m <<= 1) rs += __shfl_xor(rs, m, 64);
      if (l15 == 0) atomicAdd(&S[grow], rs);
    }
}

// partial[z] = Abf[:, zK:(z+1)K] @ hmT_all[:, zK:(z+1)K]^T  -> bf16 partials [2][NPAD][768]
__global__ __launch_bounds__(256) void k_pvsk(const u16* __restrict__ Abf, const u16* __restrict__ hmT,
                                              u16* __restrict__ part) {
  __shared__ u16 As[128 * 64], Bs[128 * 64];
  int lane = threadIdx.x & 63, wave = threadIdx.x >> 6;
  int col0 = blockIdx.x * 128, row0 = blockIdx.y * 128, kb = blockIdx.z * (NPAD / 2);
  f32x4 acc[4][4];
  f32x4 z = {0.f, 0.f, 0.f, 0.f};
  for (int i = 0; i < 4; ++i) for (int j = 0; j < 4; ++j) acc[i][j] = z;
  gemm_loop<4>(Abf + (size_t)row0 * NPAD + kb, NPAD,
               hmT + (size_t)col0 * NPAD + kb, NPAD, NPAD / 2, As, Bs, acc, lane, wave);
  u16* pp = part + (size_t)blockIdx.z * NPAD * (VV * HH);
  int wr = (wave >> 1) * 64, wc = (wave & 1) * 64, l15 = lane & 15, lq = lane >> 4;
#pragma unroll
  for (int i = 0; i < 4; ++i)
#pragma unroll
    for (int r = 0; r < 4; ++r) {
      int grow = row0 + wr + i * 16 + lq * 4 + r;
#pragma unroll
      for (int j = 0; j < 4; ++j) {
        int gcol = col0 + wc + j * 16 + l15;
        pp[(size_t)grow * (VV * HH) + gcol] = f2bf(acc[i][j][r]);
      }
    }
}

// newx = blend((p0+p1)/S, h); writes out_newx (f32) and nxb (bf16)
__global__ __launch_bounds__(256) void k_pvred(const u16* __restrict__ part, const float* __restrict__ S,
                                               const float* __restrict__ mT, const float* __restrict__ h,
                                               float* __restrict__ out_newx, u16* __restrict__ nxb) {
  int i = (blockIdx.x * 256 + threadIdx.x) * 4;   // over VV*NN*HH
  int v = i / (NN * HH);
  int rem = i - v * (NN * HH);
  int n = rem / HH;
  int j = rem - n * HH;
  int col = v * HH + j;
  u16x4 p0 = *(const u16x4*)(part + (size_t)n * (VV * HH) + col);
  u16x4 p1 = *(const u16x4*)(part + (size_t)NPAD * (VV * HH) + (size_t)n * (VV * HH) + col);
  float sc = 1.0f / (S[n] + 1e-9f);
  float mrow = mT[v * NPAD + n];
  float4 o;
  o.x = (bf2f(p0[0]) + bf2f(p1[0])) * sc;
  o.y = (bf2f(p0[1]) + bf2f(p1[1])) * sc;
  o.z = (bf2f(p0[2]) + bf2f(p1[2])) * sc;
  o.w = (bf2f(p0[3]) + bf2f(p1[3])) * sc;
  if (mrow != 0.0f) o = *(const float4*)(h + (size_t)(v * NPAD + n) * HH + j);
  *(float4*)(out_newx + (size_t)(v * NN + n) * HH + j) = o;
  u16x4 ob = { f2bf(o.x), f2bf(o.y), f2bf(o.z), f2bf(o.w) };
  *(u16x4*)(nxb + (size_t)(v * NPAD + n) * HH + j) = ob;
}

// x_new = leaky(new_x @ W_out^T + b_out), nan->0  [RT=2]
__global__ __launch_bounds__(256) void k_gemm3(const u16* __restrict__ nxb, const u16* __restrict__ woutb,
                                               const float* __restrict__ b_out, float* __restrict__ out_xnew) {
  __shared__ u16 As[64 * 64], Bs[128 * 64];
  int lane = threadIdx.x & 63, wave = threadIdx.x >> 6;
  int col0 = blockIdx.x * 128, row0 = blockIdx.y * 64, v = blockIdx.z;
  f32x4 acc[2][4];
  f32x4 z = {0.f, 0.f, 0.f, 0.f};
  for (int i = 0; i < 2; ++i) for (int j = 0; j < 4; ++j) acc[i][j] = z;
  gemm_loop<2>(nxb + (size_t)(v * NPAD + row0) * HH, HH,
               woutb + (size_t)(v * DD + col0) * HH, HH, HH, As, Bs, acc, lane, wave);
  int wr = (wave >> 1) * 32, wc = (wave & 1) * 64, l15 = lane & 15, lq = lane >> 4;
#pragma unroll
  for (int i = 0; i < 2; ++i)
#pragma unroll
    for (int r = 0; r < 4; ++r) {
      int grow = row0 + wr + i * 16 + lq * 4 + r;
      if (grow < NN) {
#pragma unroll
        for (int j = 0; j < 4; ++j) {
          int gcol = col0 + wc + j * 16 + l15;
          float val = leaky(acc[i][j][r] + b_out[v * DD + gcol]);
          if (val != val) val = 0.0f;
          out_xnew[(size_t)(v * NN + grow) * DD + gcol] = val;
        }
      }
    }
}

// y_n = sigmoid(y @ Wy^T + by)  [RT=2]
__global__ __launch_bounds__(256) void k_ygemm(const u16* __restrict__ yb, const u16* __restrict__ wyb,
                                               const float* __restrict__ by, float* __restrict__ out_yn) {
  __shared__ u16 As[64 * 64], Bs[128 * 64];
  int lane = threadIdx.x & 63, wave = threadIdx.x >> 6;
  int col0 = blockIdx.x * 128, row0 = blockIdx.y * 64;
  f32x4 acc[2][4];
  f32x4 z = {0.f, 0.f, 0.f, 0.f};
  for (int i = 0; i < 2; ++i) for (int j = 0; j < 4; ++j) acc[i][j] = z;
  gemm_loop<2>(yb + (size_t)row0 * DYY, DYY, wyb + (size_t)col0 * DYY, DYY, DYY, As, Bs, acc, lane, wave);
  int wr = (wave >> 1) * 32, wc = (wave & 1) * 64, l15 = lane & 15, lq = lane >> 4;
#pragma unroll
  for (int i = 0; i < 2; ++i)
#pragma unroll
    for (int r = 0; r < 4; ++r) {
      int grow = row0 + wr + i * 16 + lq * 4 + r;
      if (grow < NN) {
#pragma unroll
        for (int j = 0; j < 4; ++j) {
          int gcol = col0 + wc + j * 16 + l15;
          float val = acc[i][j][r] + by[gcol];
          out_yn[(size_t)grow * HH + gcol] = 1.0f / (1.0f + __expf(-val));
        }
      }
    }
}

// ---------------- launch ----------------

extern "C" void kernel_launch(void* const* d_in, const int* in_sizes, int n_in,
                              void* d_out, int out_size, void* d_ws, size_t ws_size,
                              hipStream_t stream) {
  const float* x    = (const float*)d_in[0];
  const float* y    = (const float*)d_in[1];
  const float* mask = (const float*)d_in[2];
  const float* W_in = (const float*)d_in[3];
  const float* b_in = (const float*)d_in[4];
  const float* W_out= (const float*)d_in[5];
  const float* b_out= (const float*)d_in[6];
  const float* Wy   = (const float*)d_in[7];
  const float* by   = (const float*)d_in[8];

  float* out_newx = (float*)d_out;
  float* out_xnew = out_newx + (size_t)VV * NN * HH;
  float* out_yn   = out_xnew + (size_t)VV * NN * DD;

  char* w = (char*)d_ws;
  size_t off = 0;
  auto alloc = [&](size_t bytes) -> void* {
    void* p = w + off;
    off += (bytes + 255) & ~(size_t)255;
    return p;
  };
  u16*   xb    = (u16*)alloc((size_t)VV * NPAD * DD * 2);
  u16*   yb    = (u16*)alloc((size_t)NPAD * DYY * 2);
  u16*   winb  = (u16*)alloc((size_t)VV * HH * DD * 2);
  u16*   woutb = (u16*)alloc((size_t)VV * DD * HH * 2);
  u16*   wyb   = (u16*)alloc((size_t)HH * DYY * 2);
  float* h     = (float*)alloc((size_t)VV * NPAD * HH * 4);
  u16*   qb    = (u16*)alloc((size_t)VV * NPAD * HH * 2);
  u16*   hmT   = (u16*)alloc((size_t)VV * HH * NPAD * 2);
  u16*   nxb   = (u16*)alloc((size_t)VV * NPAD * HH * 2);
  float* mT    = (float*)alloc((size_t)VV * NPAD * 4);
  float* S     = (float*)alloc((size_t)NPAD * 4);
  u16*   Abf   = (u16*)alloc((size_t)NPAD * NPAD * 2);
  // split-K partials (2 x NPAD x 768 bf16 = 18.48 MB) reuse xb, dead after k_gemm1
  u16*   pvp   = xb;
  (void)ws_size; (void)in_sizes; (void)n_in; (void)out_size;

  // conversions
  k_conv<<<384, 256, 0, stream>>>(W_in, winb, VV * HH * DD / 4);
  k_conv<<<384, 256, 0, stream>>>(W_out, woutb, VV * DD * HH / 4);
  k_conv<<<128, 256, 0, stream>>>(Wy, wyb, HH * DYY / 4);
  k_conv<<<3000, 256, 0, stream>>>(y, yb, NN * DYY / 4);
  k_convx<<<9000, 256, 0, stream>>>(x, xb);
  k_mt<<<(VV * NPAD + 255) / 256, 256, 0, stream>>>(mask, mT);
  hipMemsetAsync(S, 0, NPAD * sizeof(float), stream);

  // h, q, hmT
  k_gemm1<<<dim3(2, 94, 3), 256, 0, stream>>>(xb, winb, b_in, h);
  k_qprep<<<VV * NN, 256, 0, stream>>>(h, qb);
  k_hmt<<<dim3(94, 4, 3), dim3(64, 16), 0, stream>>>(h, mT, hmT);

  // attention (k_qk also accumulates row sums into S)
  k_qk<<<dim3(47, 94), 256, 0, stream>>>(qb, mT, Abf, S);
  k_pvsk<<<dim3(6, 47, 2), 256, 0, stream>>>(Abf, hmT, pvp);
  k_pvred<<<4500, 256, 0, stream>>>(pvp, S, mT, h, out_newx, nxb);

  // outputs
  k_gemm3<<<dim3(4, 94, 3), 256, 0, stream>>>(nxb, woutb, b_out, out_xnew);
  k_ygemm<<<dim3(2, 94), 256, 0, stream>>>(yb, wyb, by, out_yn);
}

// Round 4
// 435.065 us; speedup vs baseline: 1.1960x; 1.0643x over previous
//
#include <hip/hip_runtime.h>

#define VV 3
#define NN 6000
#define DD 512
#define HH 256
#define DYY 512
#define NPAD 6016   // 47*128
#define QK_BK 32

typedef unsigned short u16;
typedef __bf16 bf16x8 __attribute__((ext_vector_type(8)));
typedef u16 u16x8 __attribute__((ext_vector_type(8)));
typedef float f32x4 __attribute__((ext_vector_type(4)));
typedef u16 u16x4 __attribute__((ext_vector_type(4)));

__device__ __forceinline__ u16 f2bf(float f) {
  unsigned int b = __builtin_bit_cast(unsigned int, f);
  b += 0x7FFFu + ((b >> 16) & 1u);
  return (u16)(b >> 16);
}
__device__ __forceinline__ float bf2f(u16 u) {
  unsigned int b = ((unsigned int)u) << 16;
  return __builtin_bit_cast(float, b);
}
__device__ __forceinline__ float leaky(float v) { return v >= 0.0f ? v : 0.1f * v; }

// ---- stage ROWS x DEPTH bf16 tile: global row-major (ld elems) -> LDS [ROWS][DEPTH]
template<int ROWS, int DEPTH = 64>
__device__ __forceinline__ void stage(const u16* __restrict__ g, int ld, u16* s, int wave, int lane) {
  constexpr int LPR = DEPTH / 8;   // lanes per row (16B each)
  constexpr int RPC = 64 / LPR;    // rows per chunk
  constexpr int PER = ROWS / 4;    // rows per wave
  const u16* gp = g + (wave * PER + lane / LPR) * ld + (lane % LPR) * 8;
  u16* sp = s + wave * PER * DEPTH;
#pragma unroll
  for (int ch = 0; ch < PER / RPC; ++ch) {
    __builtin_amdgcn_global_load_lds(
        (const __attribute__((address_space(1))) void*)(gp + ch * RPC * ld),
        (__attribute__((address_space(3))) void*)(sp + ch * RPC * DEPTH), 16, 0, 0);
  }
}

// ---- wave computes (RT*16) x 64 outputs; block = 4 waves in 2x2 -> (RT*32) x 128 tile
template<int RT, int DEPTH = 64>
__device__ __forceinline__ void mfma_step(const u16* As, const u16* Bs, f32x4 (*acc)[4], int lane, int wave) {
  const int wr = (wave >> 1) * (RT * 16);
  const int wc = (wave & 1) * 64;
  const int l15 = lane & 15;
  const int lq = lane >> 4;
#pragma unroll
  for (int kk = 0; kk < DEPTH; kk += 32) {
    bf16x8 a[RT], b[4];
#pragma unroll
    for (int i = 0; i < RT; ++i)
      a[i] = *(const bf16x8*)(As + (wr + i * 16 + l15) * DEPTH + kk + lq * 8);
#pragma unroll
    for (int j = 0; j < 4; ++j)
      b[j] = *(const bf16x8*)(Bs + (wc + j * 16 + l15) * DEPTH + kk + lq * 8);
#pragma unroll
    for (int i = 0; i < RT; ++i)
#pragma unroll
      for (int j = 0; j < 4; ++j)
        acc[i][j] = __builtin_amdgcn_mfma_f32_16x16x32_bf16(a[i], b[j], acc[i][j], 0, 0, 0);
  }
}

template<int RT>
__device__ __forceinline__ void gemm_loop(const u16* __restrict__ A, int lda,
                                          const u16* __restrict__ B, int ldb, int K,
                                          u16* As, u16* Bs, f32x4 (*acc)[4], int lane, int wave) {
  for (int k0 = 0; k0 < K; k0 += 64) {
    stage<RT * 32>(A + k0, lda, As, wave, lane);
    stage<128>(B + k0, ldb, Bs, wave, lane);
    __syncthreads();
    mfma_step<RT>(As, Bs, acc, lane, wave);
    __syncthreads();
  }
}

// ---------------- elementwise / prep kernels ----------------

__global__ __launch_bounds__(256) void k_conv(const float* __restrict__ in, u16* __restrict__ out, int n4) {
  int i = blockIdx.x * 256 + threadIdx.x;
  if (i >= n4) return;
  float4 f = ((const float4*)in)[i];
  u16x4 o = { f2bf(f.x), f2bf(f.y), f2bf(f.z), f2bf(f.w) };
  *(u16x4*)(out + i * 4) = o;
}

// x (V,N,D) f32 -> bf16 with per-v row padding to NPAD
__global__ __launch_bounds__(256) void k_convx(const float* __restrict__ x, u16* __restrict__ xb) {
  int i = blockIdx.x * 256 + threadIdx.x;     // 2,304,000 quads
  if (i >= VV * NN * DD / 4) return;
  int idx = i * 4;
  int v = idx / (NN * DD);
  int rem = idx - v * (NN * DD);
  int n = rem / DD;
  int d = rem - n * DD;
  float4 f = *(const float4*)(x + idx);
  u16x4 o = { f2bf(f.x), f2bf(f.y), f2bf(f.z), f2bf(f.w) };
  *(u16x4*)(xb + (size_t)(v * NPAD + n) * DD + d) = o;
}

// mT[v][n] padded (zeros beyond NN)
__global__ __launch_bounds__(256) void k_mt(const float* __restrict__ mask, float* __restrict__ mT) {
  int i = blockIdx.x * 256 + threadIdx.x;
  if (i >= VV * NPAD) return;
  int v = i / NPAD, n = i - v * NPAD;
  mT[i] = (n < NN) ? mask[n * VV + v] : 0.0f;
}

// q = h / max(||h||,1e-12) -> bf16; one block per (v,n) row
__global__ __launch_bounds__(256) void k_qprep(const float* __restrict__ h, u16* __restrict__ qb) {
  int b = blockIdx.x;
  int v = b / NN, n = b - v * NN;
  int t = threadIdx.x;
  float val = h[(size_t)(v * NPAD + n) * HH + t];
  float ss = val * val;
#pragma unroll
  for (int o = 32; o > 0; o >>= 1) ss += __shfl_down(ss, o, 64);
  __shared__ float red[4];
  if ((t & 63) == 0) red[t >> 6] = ss;
  __syncthreads();
  float inv = 1.0f / fmaxf(sqrtf(red[0] + red[1] + red[2] + red[3]), 1e-12f);
  qb[(size_t)(v * NPAD + n) * HH + t] = f2bf(val * inv);
}

// hmT[v][j][m] = mT[v][m]*h[v][m][j] (bf16, zero for m>=NN), 64x64 LDS transpose
__global__ __launch_bounds__(1024) void k_hmt(const float* __restrict__ h, const float* __restrict__ mT,
                                              u16* __restrict__ hmT) {
  __shared__ float t[64][65];
  int m0 = blockIdx.x * 64, j0 = blockIdx.y * 64, v = blockIdx.z;
  int tx = threadIdx.x, ty = threadIdx.y;
#pragma unroll
  for (int p = 0; p < 4; ++p) {
    int ml = ty + p * 16;
    int m = m0 + ml;
    float val = 0.0f;
    if (m < NN) val = mT[v * NPAD + m] * h[(size_t)(v * NPAD + m) * HH + j0 + tx];
    t[ml][tx] = val;
  }
  __syncthreads();
#pragma unroll
  for (int p = 0; p < 4; ++p) {
    int j = j0 + ty + p * 16;
    hmT[(size_t)(v * HH + j) * NPAD + m0 + tx] = f2bf(t[tx][ty + p * 16]);
  }
}

// ---------------- GEMM kernels ----------------

// h = leaky(x @ W_in^T + b_in)   [RT=2: 64x128 tile]
__global__ __launch_bounds__(256) void k_gemm1(const u16* __restrict__ xb, const u16* __restrict__ winb,
                                               const float* __restrict__ b_in, float* __restrict__ h) {
  __shared__ u16 As[64 * 64], Bs[128 * 64];
  int lane = threadIdx.x & 63, wave = threadIdx.x >> 6;
  int col0 = blockIdx.x * 128, row0 = blockIdx.y * 64, v = blockIdx.z;
  f32x4 acc[2][4];
  f32x4 z = {0.f, 0.f, 0.f, 0.f};
  for (int i = 0; i < 2; ++i) for (int j = 0; j < 4; ++j) acc[i][j] = z;
  gemm_loop<2>(xb + (size_t)(v * NPAD + row0) * DD, DD,
               winb + (size_t)(v * HH + col0) * DD, DD, DD, As, Bs, acc, lane, wave);
  int wr = (wave >> 1) * 32, wc = (wave & 1) * 64, l15 = lane & 15, lq = lane >> 4;
#pragma unroll
  for (int i = 0; i < 2; ++i)
#pragma unroll
    for (int r = 0; r < 4; ++r) {
      int grow = row0 + wr + i * 16 + lq * 4 + r;
      if (grow < NN) {
#pragma unroll
        for (int j = 0; j < 4; ++j) {
          int gcol = col0 + wc + j * 16 + l15;
          h[(size_t)(v * NPAD + grow) * HH + gcol] = leaky(acc[i][j][r] + b_in[v * HH + gcol]);
        }
      }
    }
}

// A = max_v mask*exp(q_v q_v^T / beta), diag zeroed, bf16; accumulates row sums into S.
// A is SYMMETRIC: only upper-triangle tiles computed (y <= 2x+1); each value written
// direct (coalesced) + mirrored via LDS transpose. BK=32, 36 KB LDS -> 4 blocks/CU.
__global__ __launch_bounds__(256, 4) void k_qk(const u16* __restrict__ qb, const float* __restrict__ mT,
                                               u16* __restrict__ Abf, float* __restrict__ S) {
  __shared__ u16 sh[VV * 192 * QK_BK];   // 36864 B; reused as Tr[128][72] in epilogue
  u16* As = sh;                          // VV x [64][QK_BK]
  u16* Bs = sh + VV * 64 * QK_BK;        // VV x [128][QK_BK]
  int lane = threadIdx.x & 63, wave = threadIdx.x >> 6;
  // triangle decode: bid in [x(x+1), (x+1)(x+2))
  int bid = blockIdx.x;
  int x = (int)((sqrtf((float)(4 * bid + 1)) - 1.0f) * 0.5f);
  while ((x + 1) * (x + 2) <= bid) ++x;
  while (x * (x + 1) > bid) --x;
  int y = bid - x * (x + 1);
  int col0 = x * 128, row0 = y * 64;

  f32x4 z = {0.f, 0.f, 0.f, 0.f};
  f32x4 acc[VV][2][4];
  for (int v = 0; v < VV; ++v)
    for (int i = 0; i < 2; ++i)
      for (int j = 0; j < 4; ++j) acc[v][i][j] = z;
  for (int k0 = 0; k0 < HH; k0 += QK_BK) {
#pragma unroll
    for (int v = 0; v < VV; ++v) {
      stage<64, QK_BK>(qb + (size_t)(v * NPAD + row0) * HH + k0, HH, As + v * 64 * QK_BK, wave, lane);
      stage<128, QK_BK>(qb + (size_t)(v * NPAD + col0) * HH + k0, HH, Bs + v * 128 * QK_BK, wave, lane);
    }
    __syncthreads();
#pragma unroll
    for (int v = 0; v < VV; ++v)
      mfma_step<2, QK_BK>(As + v * 64 * QK_BK, Bs + v * 128 * QK_BK, acc[v], lane, wave);
    __syncthreads();
  }
  int wr = (wave >> 1) * 32, wc = (wave & 1) * 64, l15 = lane & 15, lq = lane >> 4;
  float mc[VV][4];
#pragma unroll
  for (int v = 0; v < VV; ++v)
#pragma unroll
    for (int j = 0; j < 4; ++j) mc[v][j] = mT[v * NPAD + col0 + wc + j * 16 + l15];
  float cs[4] = {0.f, 0.f, 0.f, 0.f};   // column sums (mirror contributions to S)
#pragma unroll
  for (int i = 0; i < 2; ++i)
#pragma unroll
    for (int r = 0; r < 4; ++r) {
      int grow = row0 + wr + i * 16 + lq * 4 + r;
      float mr0 = mT[grow];
      float mr1 = mT[NPAD + grow];
      float mr2 = mT[2 * NPAD + grow];
      float rs = 0.0f;
#pragma unroll
      for (int j = 0; j < 4; ++j) {
        int gcol = col0 + wc + j * 16 + l15;
        float e0 = (mr0 * mc[0][j] != 0.0f) ? __expf(acc[0][i][j][r] * 5.0f) : 0.0f;
        float e1 = (mr1 * mc[1][j] != 0.0f) ? __expf(acc[1][i][j][r] * 5.0f) : 0.0f;
        float e2 = (mr2 * mc[2][j] != 0.0f) ? __expf(acc[2][i][j][r] * 5.0f) : 0.0f;
        float val = fmaxf(fmaxf(e0, e1), e2);
        if (grow == gcol) val = 0.0f;
        bool strict = gcol > grow;
        if (gcol >= grow) {
          Abf[(size_t)grow * NPAD + gcol] = f2bf(val);
          rs += val;
        }
        float mv = strict ? val : 0.0f;
        cs[j] += mv;
        sh[(wc + j * 16 + l15) * 72 + (wr + i * 16 + lq * 4 + r)] = f2bf(mv);  // Tr[cc][gr]
      }
#pragma unroll
      for (int m = 1; m < 16; m <<= 1) rs += __shfl_xor(rs, m, 64);
      if (l15 == 0) atomicAdd(&S[grow], rs);
    }
#pragma unroll
  for (int j = 0; j < 4; ++j) {
    float c = cs[j];
    c += __shfl_xor(c, 16, 64);
    c += __shfl_xor(c, 32, 64);
    if (lq == 0 && c != 0.0f) atomicAdd(&S[col0 + wc + j * 16 + l15], c);
  }
  __syncthreads();
  // mirror write: A[col0+cc][row0+gr] for cc,gr with global row > global col
  if (col0 >= row0 + 64) {   // fully-upper tile: unconditional, coalesced 16B stores
    int c = threadIdx.x & 7, rr = threadIdx.x >> 3;   // 8 chunks x 32 rows
#pragma unroll
    for (int p = 0; p < 4; ++p) {
      int cc = rr + p * 32;
      u16x8 chunk = *(const u16x8*)(sh + cc * 72 + c * 8);
      *(u16x8*)(Abf + (size_t)(col0 + cc) * NPAD + row0 + c * 8) = chunk;
    }
  } else {                    // straddle tile (94 of 2256): predicated scalar
    for (int idx = threadIdx.x; idx < 128 * 64; idx += 256) {
      int cc = idx >> 6, gr = idx & 63;
      int R = col0 + cc, C = row0 + gr;
      if (R > C) Abf[(size_t)R * NPAD + C] = sh[cc * 72 + gr];
    }
  }
}

// partial[z] = Abf[:, zK:(z+1)K] @ hmT_all[:, zK:(z+1)K]^T  -> bf16 partials [2][NPAD][768]
__global__ __launch_bounds__(256) void k_pvsk(const u16* __restrict__ Abf, const u16* __restrict__ hmT,
                                              u16* __restrict__ part) {
  __shared__ u16 As[128 * 64], Bs[128 * 64];
  int lane = threadIdx.x & 63, wave = threadIdx.x >> 6;
  int col0 = blockIdx.x * 128, row0 = blockIdx.y * 128, kb = blockIdx.z * (NPAD / 2);
  f32x4 acc[4][4];
  f32x4 z = {0.f, 0.f, 0.f, 0.f};
  for (int i = 0; i < 4; ++i) for (int j = 0; j < 4; ++j) acc[i][j] = z;
  gemm_loop<4>(Abf + (size_t)row0 * NPAD + kb, NPAD,
               hmT + (size_t)col0 * NPAD + kb, NPAD, NPAD / 2, As, Bs, acc, lane, wave);
  u16* pp = part + (size_t)blockIdx.z * NPAD * (VV * HH);
  int wr = (wave >> 1) * 64, wc = (wave & 1) * 64, l15 = lane & 15, lq = lane >> 4;
#pragma unroll
  for (int i = 0; i < 4; ++i)
#pragma unroll
    for (int r = 0; r < 4; ++r) {
      int grow = row0 + wr + i * 16 + lq * 4 + r;
#pragma unroll
      for (int j = 0; j < 4; ++j) {
        int gcol = col0 + wc + j * 16 + l15;
        pp[(size_t)grow * (VV * HH) + gcol] = f2bf(acc[i][j][r]);
      }
    }
}

// newx = blend((p0+p1)/S, h); writes out_newx (f32) and nxb (bf16)
__global__ __launch_bounds__(256) void k_pvred(const u16* __restrict__ part, const float* __restrict__ S,
                                               const float* __restrict__ mT, const float* __restrict__ h,
                                               float* __restrict__ out_newx, u16* __restrict__ nxb) {
  int i = (blockIdx.x * 256 + threadIdx.x) * 4;   // over VV*NN*HH
  int v = i / (NN * HH);
  int rem = i - v * (NN * HH);
  int n = rem / HH;
  int j = rem - n * HH;
  int col = v * HH + j;
  u16x4 p0 = *(const u16x4*)(part + (size_t)n * (VV * HH) + col);
  u16x4 p1 = *(const u16x4*)(part + (size_t)NPAD * (VV * HH) + (size_t)n * (VV * HH) + col);
  float sc = 1.0f / (S[n] + 1e-9f);
  float mrow = mT[v * NPAD + n];
  float4 o;
  o.x = (bf2f(p0[0]) + bf2f(p1[0])) * sc;
  o.y = (bf2f(p0[1]) + bf2f(p1[1])) * sc;
  o.z = (bf2f(p0[2]) + bf2f(p1[2])) * sc;
  o.w = (bf2f(p0[3]) + bf2f(p1[3])) * sc;
  if (mrow != 0.0f) o = *(const float4*)(h + (size_t)(v * NPAD + n) * HH + j);
  *(float4*)(out_newx + (size_t)(v * NN + n) * HH + j) = o;
  u16x4 ob = { f2bf(o.x), f2bf(o.y), f2bf(o.z), f2bf(o.w) };
  *(u16x4*)(nxb + (size_t)(v * NPAD + n) * HH + j) = ob;
}

// x_new = leaky(new_x @ W_out^T + b_out), nan->0  [RT=2]
__global__ __launch_bounds__(256) void k_gemm3(const u16* __restrict__ nxb, const u16* __restrict__ woutb,
                                               const float* __restrict__ b_out, float* __restrict__ out_xnew) {
  __shared__ u16 As[64 * 64], Bs[128 * 64];
  int lane = threadIdx.x & 63, wave = threadIdx.x >> 6;
  int col0 = blockIdx.x * 128, row0 = blockIdx.y * 64, v = blockIdx.z;
  f32x4 acc[2][4];
  f32x4 z = {0.f, 0.f, 0.f, 0.f};
  for (int i = 0; i < 2; ++i) for (int j = 0; j < 4; ++j) acc[i][j] = z;
  gemm_loop<2>(nxb + (size_t)(v * NPAD + row0) * HH, HH,
               woutb + (size_t)(v * DD + col0) * HH, HH, HH, As, Bs, acc, lane, wave);
  int wr = (wave >> 1) * 32, wc = (wave & 1) * 64, l15 = lane & 15, lq = lane >> 4;
#pragma unroll
  for (int i = 0; i < 2; ++i)
#pragma unroll
    for (int r = 0; r < 4; ++r) {
      int grow = row0 + wr + i * 16 + lq * 4 + r;
      if (grow < NN) {
#pragma unroll
        for (int j = 0; j < 4; ++j) {
          int gcol = col0 + wc + j * 16 + l15;
          float val = leaky(acc[i][j][r] + b_out[v * DD + gcol]);
          if (val != val) val = 0.0f;
          out_xnew[(size_t)(v * NN + grow) * DD + gcol] = val;
        }
      }
    }
}

// y_n = sigmoid(y @ Wy^T + by)  [RT=2]
__global__ __launch_bounds__(256) void k_ygemm(const u16* __restrict__ yb, const u16* __restrict__ wyb,
                                               const float* __restrict__ by, float* __restrict__ out_yn) {
  __shared__ u16 As[64 * 64], Bs[128 * 64];
  int lane = threadIdx.x & 63, wave = threadIdx.x >> 6;
  int col0 = blockIdx.x * 128, row0 = blockIdx.y * 64;
  f32x4 acc[2][4];
  f32x4 z = {0.f, 0.f, 0.f, 0.f};
  for (int i = 0; i < 2; ++i) for (int j = 0; j < 4; ++j) acc[i][j] = z;
  gemm_loop<2>(yb + (size_t)row0 * DYY, DYY, wyb + (size_t)col0 * DYY, DYY, DYY, As, Bs, acc, lane, wave);
  int wr = (wave >> 1) * 32, wc = (wave & 1) * 64, l15 = lane & 15, lq = lane >> 4;
#pragma unroll
  for (int i = 0; i < 2; ++i)
#pragma unroll
    for (int r = 0; r < 4; ++r) {
      int grow = row0 + wr + i * 16 + lq * 4 + r;
      if (grow < NN) {
#pragma unroll
        for (int j = 0; j < 4; ++j) {
          int gcol = col0 + wc + j * 16 + l15;
          float val = acc[i][j][r] + by[gcol];
          out_yn[(size_t)grow * HH + gcol] = 1.0f / (1.0f + __expf(-val));
        }
      }
    }
}

// ---------------- launch ----------------

extern "C" void kernel_launch(void* const* d_in, const int* in_sizes, int n_in,
                              void* d_out, int out_size, void* d_ws, size_t ws_size,
                              hipStream_t stream) {
  const float* x    = (const float*)d_in[0];
  const float* y    = (const float*)d_in[1];
  const float* mask = (const float*)d_in[2];
  const float* W_in = (const float*)d_in[3];
  const float* b_in = (const float*)d_in[4];
  const float* W_out= (const float*)d_in[5];
  const float* b_out= (const float*)d_in[6];
  const float* Wy   = (const float*)d_in[7];
  const float* by   = (const float*)d_in[8];

  float* out_newx = (float*)d_out;
  float* out_xnew = out_newx + (size_t)VV * NN * HH;
  float* out_yn   = out_xnew + (size_t)VV * NN * DD;

  char* w = (char*)d_ws;
  size_t off = 0;
  auto alloc = [&](size_t bytes) -> void* {
    void* p = w + off;
    off += (bytes + 255) & ~(size_t)255;
    return p;
  };
  u16*   xb    = (u16*)alloc((size_t)VV * NPAD * DD * 2);
  u16*   yb    = (u16*)alloc((size_t)NPAD * DYY * 2);
  u16*   winb  = (u16*)alloc((size_t)VV * HH * DD * 2);
  u16*   woutb = (u16*)alloc((size_t)VV * DD * HH * 2);
  u16*   wyb   = (u16*)alloc((size_t)HH * DYY * 2);
  float* h     = (float*)alloc((size_t)VV * NPAD * HH * 4);
  u16*   qb    = (u16*)alloc((size_t)VV * NPAD * HH * 2);
  u16*   hmT   = (u16*)alloc((size_t)VV * HH * NPAD * 2);
  u16*   nxb   = (u16*)alloc((size_t)VV * NPAD * HH * 2);
  float* mT    = (float*)alloc((size_t)VV * NPAD * 4);
  float* S     = (float*)alloc((size_t)NPAD * 4);
  u16*   Abf   = (u16*)alloc((size_t)NPAD * NPAD * 2);
  // split-K partials (2 x NPAD x 768 bf16 = 18.48 MB) reuse xb, dead after k_gemm1
  u16*   pvp   = xb;
  (void)ws_size; (void)in_sizes; (void)n_in; (void)out_size;

  // conversions
  k_conv<<<384, 256, 0, stream>>>(W_in, winb, VV * HH * DD / 4);
  k_conv<<<384, 256, 0, stream>>>(W_out, woutb, VV * DD * HH / 4);
  k_conv<<<128, 256, 0, stream>>>(Wy, wyb, HH * DYY / 4);
  k_conv<<<3000, 256, 0, stream>>>(y, yb, NN * DYY / 4);
  k_convx<<<9000, 256, 0, stream>>>(x, xb);
  k_mt<<<(VV * NPAD + 255) / 256, 256, 0, stream>>>(mask, mT);
  hipMemsetAsync(S, 0, NPAD * sizeof(float), stream);

  // h, q, hmT
  k_gemm1<<<dim3(2, 94, 3), 256, 0, stream>>>(xb, winb, b_in, h);
  k_qprep<<<VV * NN, 256, 0, stream>>>(h, qb);
  k_hmt<<<dim3(94, 4, 3), dim3(64, 16), 0, stream>>>(h, mT, hmT);

  // attention (k_qk: upper-triangle tiles only; also accumulates row sums into S)
  k_qk<<<2256, 256, 0, stream>>>(qb, mT, Abf, S);
  k_pvsk<<<dim3(6, 47, 2), 256, 0, stream>>>(Abf, hmT, pvp);
  k_pvred<<<4500, 256, 0, stream>>>(pvp, S, mT, h, out_newx, nxb);

  // outputs
  k_gemm3<<<dim3(4, 94, 3), 256, 0, stream>>>(nxb, woutb, b_out, out_xnew);
  k_ygemm<<<dim3(2, 94), 256, 0, stream>>>(yb, wyb, by, out_yn);
}

// Round 5
// 387.640 us; speedup vs baseline: 1.3424x; 1.1223x over previous
//
#include <hip/hip_runtime.h>

#define VV 3
#define NN 6000
#define DD 512
#define HH 256
#define DYY 512
#define NPAD 6016   // 47*128
#define QK_BK 32
#define QK_HALF (VV * 192 * QK_BK)   // u16 elems per staging buffer (36864 B)

typedef unsigned short u16;
typedef __bf16 bf16x8 __attribute__((ext_vector_type(8)));
typedef u16 u16x8 __attribute__((ext_vector_type(8)));
typedef float f32x4 __attribute__((ext_vector_type(4)));
typedef u16 u16x4 __attribute__((ext_vector_type(4)));

__device__ __forceinline__ u16 f2bf(float f) {
  unsigned int b = __builtin_bit_cast(unsigned int, f);
  b += 0x7FFFu + ((b >> 16) & 1u);
  return (u16)(b >> 16);
}
__device__ __forceinline__ float bf2f(u16 u) {
  unsigned int b = ((unsigned int)u) << 16;
  return __builtin_bit_cast(float, b);
}
__device__ __forceinline__ float leaky(float v) { return v >= 0.0f ? v : 0.1f * v; }

// ---- stage ROWS x DEPTH bf16 tile: global row-major (ld elems) -> LDS [ROWS][DEPTH]
template<int ROWS, int DEPTH = 64>
__device__ __forceinline__ void stage(const u16* __restrict__ g, int ld, u16* s, int wave, int lane) {
  constexpr int LPR = DEPTH / 8;   // lanes per row (16B each)
  constexpr int RPC = 64 / LPR;    // rows per chunk
  constexpr int PER = ROWS / 4;    // rows per wave
  const u16* gp = g + (wave * PER + lane / LPR) * ld + (lane % LPR) * 8;
  u16* sp = s + wave * PER * DEPTH;
#pragma unroll
  for (int ch = 0; ch < PER / RPC; ++ch) {
    __builtin_amdgcn_global_load_lds(
        (const __attribute__((address_space(1))) void*)(gp + ch * RPC * ld),
        (__attribute__((address_space(3))) void*)(sp + ch * RPC * DEPTH), 16, 0, 0);
  }
}

// ---- wave computes (RT*16) x 64 outputs; block = 4 waves in 2x2 -> (RT*32) x 128 tile
template<int RT, int DEPTH = 64>
__device__ __forceinline__ void mfma_step(const u16* As, const u16* Bs, f32x4 (*acc)[4], int lane, int wave) {
  const int wr = (wave >> 1) * (RT * 16);
  const int wc = (wave & 1) * 64;
  const int l15 = lane & 15;
  const int lq = lane >> 4;
#pragma unroll
  for (int kk = 0; kk < DEPTH; kk += 32) {
    bf16x8 a[RT], b[4];
#pragma unroll
    for (int i = 0; i < RT; ++i)
      a[i] = *(const bf16x8*)(As + (wr + i * 16 + l15) * DEPTH + kk + lq * 8);
#pragma unroll
    for (int j = 0; j < 4; ++j)
      b[j] = *(const bf16x8*)(Bs + (wc + j * 16 + l15) * DEPTH + kk + lq * 8);
#pragma unroll
    for (int i = 0; i < RT; ++i)
#pragma unroll
      for (int j = 0; j < 4; ++j)
        acc[i][j] = __builtin_amdgcn_mfma_f32_16x16x32_bf16(a[i], b[j], acc[i][j], 0, 0, 0);
  }
}

// single-buffered K-loop (used by k_gemm3)
template<int RT>
__device__ __forceinline__ void gemm_loop(const u16* __restrict__ A, int lda,
                                          const u16* __restrict__ B, int ldb, int K,
                                          u16* As, u16* Bs, f32x4 (*acc)[4], int lane, int wave) {
  for (int k0 = 0; k0 < K; k0 += 64) {
    stage<RT * 32>(A + k0, lda, As, wave, lane);
    stage<128>(B + k0, ldb, Bs, wave, lane);
    __syncthreads();
    mfma_step<RT>(As, Bs, acc, lane, wave);
    __syncthreads();
  }
}

// double-buffered K-loop: next slice's global_load_lds issued after the barrier,
// in flight during current slice's MFMA. As/Bs are bases of 2 buffers each.
template<int RT>
__device__ __forceinline__ void gemm_loop_db(const u16* __restrict__ A, int lda,
                                             const u16* __restrict__ B, int ldb, int K,
                                             u16* As, u16* Bs, f32x4 (*acc)[4], int lane, int wave) {
  const int niter = K / 64;
  stage<RT * 32>(A, lda, As, wave, lane);
  stage<128>(B, ldb, Bs, wave, lane);
  for (int it = 0; it < niter; ++it) {
    __syncthreads();
    int nb = (it + 1) & 1;
    if (it + 1 < niter) {
      stage<RT * 32>(A + (it + 1) * 64, lda, As + nb * RT * 32 * 64, wave, lane);
      stage<128>(B + (it + 1) * 64, ldb, Bs + nb * 128 * 64, wave, lane);
    }
    int cb = it & 1;
    mfma_step<RT>(As + cb * RT * 32 * 64, Bs + cb * 128 * 64, acc, lane, wave);
  }
  __syncthreads();
}

// ---------------- elementwise / prep kernels ----------------

__global__ __launch_bounds__(256) void k_conv(const float* __restrict__ in, u16* __restrict__ out, int n4) {
  int i = blockIdx.x * 256 + threadIdx.x;
  if (i >= n4) return;
  float4 f = ((const float4*)in)[i];
  u16x4 o = { f2bf(f.x), f2bf(f.y), f2bf(f.z), f2bf(f.w) };
  *(u16x4*)(out + i * 4) = o;
}

// x (V,N,D) f32 -> bf16 with per-v row padding to NPAD
__global__ __launch_bounds__(256) void k_convx(const float* __restrict__ x, u16* __restrict__ xb) {
  int i = blockIdx.x * 256 + threadIdx.x;     // 2,304,000 quads
  if (i >= VV * NN * DD / 4) return;
  int idx = i * 4;
  int v = idx / (NN * DD);
  int rem = idx - v * (NN * DD);
  int n = rem / DD;
  int d = rem - n * DD;
  float4 f = *(const float4*)(x + idx);
  u16x4 o = { f2bf(f.x), f2bf(f.y), f2bf(f.z), f2bf(f.w) };
  *(u16x4*)(xb + (size_t)(v * NPAD + n) * DD + d) = o;
}

// mT[v][n] padded (zeros beyond NN)
__global__ __launch_bounds__(256) void k_mt(const float* __restrict__ mask, float* __restrict__ mT) {
  int i = blockIdx.x * 256 + threadIdx.x;
  if (i >= VV * NPAD) return;
  int v = i / NPAD, n = i - v * NPAD;
  mT[i] = (n < NN) ? mask[n * VV + v] : 0.0f;
}

// q = h / max(||h||,1e-12) -> bf16; one block per (v,n) row
__global__ __launch_bounds__(256) void k_qprep(const float* __restrict__ h, u16* __restrict__ qb) {
  int b = blockIdx.x;
  int v = b / NN, n = b - v * NN;
  int t = threadIdx.x;
  float val = h[(size_t)(v * NPAD + n) * HH + t];
  float ss = val * val;
#pragma unroll
  for (int o = 32; o > 0; o >>= 1) ss += __shfl_down(ss, o, 64);
  __shared__ float red[4];
  if ((t & 63) == 0) red[t >> 6] = ss;
  __syncthreads();
  float inv = 1.0f / fmaxf(sqrtf(red[0] + red[1] + red[2] + red[3]), 1e-12f);
  qb[(size_t)(v * NPAD + n) * HH + t] = f2bf(val * inv);
}

// hmT[v][j][m] = mT[v][m]*h[v][m][j] (bf16, zero for m>=NN), 64x64 LDS transpose
__global__ __launch_bounds__(1024) void k_hmt(const float* __restrict__ h, const float* __restrict__ mT,
                                              u16* __restrict__ hmT) {
  __shared__ float t[64][65];
  int m0 = blockIdx.x * 64, j0 = blockIdx.y * 64, v = blockIdx.z;
  int tx = threadIdx.x, ty = threadIdx.y;
#pragma unroll
  for (int p = 0; p < 4; ++p) {
    int ml = ty + p * 16;
    int m = m0 + ml;
    float val = 0.0f;
    if (m < NN) val = mT[v * NPAD + m] * h[(size_t)(v * NPAD + m) * HH + j0 + tx];
    t[ml][tx] = val;
  }
  __syncthreads();
#pragma unroll
  for (int p = 0; p < 4; ++p) {
    int j = j0 + ty + p * 16;
    hmT[(size_t)(v * HH + j) * NPAD + m0 + tx] = f2bf(t[tx][ty + p * 16]);
  }
}

// ---------------- GEMM kernels ----------------

// h = leaky(x @ W_in^T + b_in)   [RT=2, double-buffered]
__global__ __launch_bounds__(256, 3) void k_gemm1(const u16* __restrict__ xb, const u16* __restrict__ winb,
                                                  const float* __restrict__ b_in, float* __restrict__ h) {
  __shared__ u16 As[2 * 64 * 64], Bs[2 * 128 * 64];
  int lane = threadIdx.x & 63, wave = threadIdx.x >> 6;
  int col0 = blockIdx.x * 128, row0 = blockIdx.y * 64, v = blockIdx.z;
  f32x4 acc[2][4];
  f32x4 z = {0.f, 0.f, 0.f, 0.f};
  for (int i = 0; i < 2; ++i) for (int j = 0; j < 4; ++j) acc[i][j] = z;
  gemm_loop_db<2>(xb + (size_t)(v * NPAD + row0) * DD, DD,
                  winb + (size_t)(v * HH + col0) * DD, DD, DD, As, Bs, acc, lane, wave);
  int wr = (wave >> 1) * 32, wc = (wave & 1) * 64, l15 = lane & 15, lq = lane >> 4;
#pragma unroll
  for (int i = 0; i < 2; ++i)
#pragma unroll
    for (int r = 0; r < 4; ++r) {
      int grow = row0 + wr + i * 16 + lq * 4 + r;
      if (grow < NN) {
#pragma unroll
        for (int j = 0; j < 4; ++j) {
          int gcol = col0 + wc + j * 16 + l15;
          h[(size_t)(v * NPAD + grow) * HH + gcol] = leaky(acc[i][j][r] + b_in[v * HH + gcol]);
        }
      }
    }
}

// A = max_v mask*exp(q_v q_v^T / beta), diag zeroed, bf16; accumulates row sums into S.
// Upper-triangle tiles only (y <= 2x+1); double-buffered staging; epilogue builds the
// tile in LDS and writes direct + mirror with 16-B vector stores.
__global__ __launch_bounds__(256, 2) void k_qk(const u16* __restrict__ qb, const float* __restrict__ mT,
                                               u16* __restrict__ Abf, float* __restrict__ S) {
  extern __shared__ u16 sh[];   // 2 * QK_HALF u16 = 73728 B
  int lane = threadIdx.x & 63, wave = threadIdx.x >> 6;
  // triangle decode: bid in [x(x+1), (x+1)(x+2))
  int bid = blockIdx.x;
  int x = (int)((sqrtf((float)(4 * bid + 1)) - 1.0f) * 0.5f);
  while ((x + 1) * (x + 2) <= bid) ++x;
  while (x * (x + 1) > bid) --x;
  int y = bid - x * (x + 1);
  int col0 = x * 128, row0 = y * 64;

  f32x4 z = {0.f, 0.f, 0.f, 0.f};
  f32x4 acc[VV][2][4];
  for (int v = 0; v < VV; ++v)
    for (int i = 0; i < 2; ++i)
      for (int j = 0; j < 4; ++j) acc[v][i][j] = z;

  // staging helper: A-panels (3 x 64 x BK) then B-panels (3 x 128 x BK)
  auto qk_stage = [&](int k0, u16* buf) {
#pragma unroll
    for (int v = 0; v < VV; ++v) {
      stage<64, QK_BK>(qb + (size_t)(v * NPAD + row0) * HH + k0, HH, buf + v * 64 * QK_BK, wave, lane);
      stage<128, QK_BK>(qb + (size_t)(v * NPAD + col0) * HH + k0, HH,
                        buf + VV * 64 * QK_BK + v * 128 * QK_BK, wave, lane);
    }
  };

  qk_stage(0, sh);
#pragma unroll
  for (int it = 0; it < HH / QK_BK; ++it) {
    __syncthreads();
    if (it + 1 < HH / QK_BK)
      qk_stage((it + 1) * QK_BK, sh + ((it + 1) & 1) * QK_HALF);
    u16* cur = sh + (it & 1) * QK_HALF;
#pragma unroll
    for (int v = 0; v < VV; ++v)
      mfma_step<2, QK_BK>(cur + v * 64 * QK_BK, cur + VV * 64 * QK_BK + v * 128 * QK_BK,
                          acc[v], lane, wave);
  }
  __syncthreads();

  // epilogue: build tile in LDS (Dir [64][136]), transpose (Tr [128][72]); S sums.
  u16* Dir = sh;               // 64*136 = 8704 u16
  u16* Tr  = sh + 64 * 136;    // 128*72 = 9216 u16
  int wr = (wave >> 1) * 32, wc = (wave & 1) * 64, l15 = lane & 15, lq = lane >> 4;
  float mc[VV][4];
#pragma unroll
  for (int v = 0; v < VV; ++v)
#pragma unroll
    for (int j = 0; j < 4; ++j) mc[v][j] = mT[v * NPAD + col0 + wc + j * 16 + l15];
  float cs[4] = {0.f, 0.f, 0.f, 0.f};   // column sums (mirror contributions to S)
#pragma unroll
  for (int i = 0; i < 2; ++i)
#pragma unroll
    for (int r = 0; r < 4; ++r) {
      int lrow = wr + i * 16 + lq * 4 + r;
      int grow = row0 + lrow;
      float mr0 = mT[grow];
      float mr1 = mT[NPAD + grow];
      float mr2 = mT[2 * NPAD + grow];
      float rs = 0.0f;
#pragma unroll
      for (int j = 0; j < 4; ++j) {
        int lcol = wc + j * 16 + l15;
        int gcol = col0 + lcol;
        float e0 = (mr0 * mc[0][j] != 0.0f) ? __expf(acc[0][i][j][r] * 5.0f) : 0.0f;
        float e1 = (mr1 * mc[1][j] != 0.0f) ? __expf(acc[1][i][j][r] * 5.0f) : 0.0f;
        float e2 = (mr2 * mc[2][j] != 0.0f) ? __expf(acc[2][i][j][r] * 5.0f) : 0.0f;
        float val = fmaxf(fmaxf(e0, e1), e2);
        if (grow == gcol) val = 0.0f;
        Dir[lrow * 136 + lcol] = f2bf(val);
        float mv = (gcol > grow) ? val : 0.0f;
        Tr[lcol * 72 + lrow] = f2bf(mv);
        if (gcol >= grow) rs += val;
        cs[j] += mv;
      }
#pragma unroll
      for (int m = 1; m < 16; m <<= 1) rs += __shfl_xor(rs, m, 64);
      if (l15 == 0 && rs != 0.0f) atomicAdd(&S[grow], rs);
    }
#pragma unroll
  for (int j = 0; j < 4; ++j) {
    float c = cs[j];
    c += __shfl_xor(c, 16, 64);
    c += __shfl_xor(c, 32, 64);
    if (lq == 0 && c != 0.0f) atomicAdd(&S[col0 + wc + j * 16 + l15], c);
  }
  __syncthreads();
  if (col0 >= row0 + 64) {   // fully-upper tile: vector stores, full 128-B lines
    int c8 = threadIdx.x & 15, rr = threadIdx.x >> 4;
#pragma unroll
    for (int p = 0; p < 4; ++p) {
      int row = rr + p * 16;
      u16x8 chunk = *(const u16x8*)(Dir + row * 136 + c8 * 8);
      *(u16x8*)(Abf + (size_t)(row0 + row) * NPAD + col0 + c8 * 8) = chunk;
    }
    int c = threadIdx.x & 7; rr = threadIdx.x >> 3;
#pragma unroll
    for (int p = 0; p < 4; ++p) {
      int cc = rr + p * 32;
      u16x8 chunk = *(const u16x8*)(Tr + cc * 72 + c * 8);
      *(u16x8*)(Abf + (size_t)(col0 + cc) * NPAD + row0 + c * 8) = chunk;
    }
  } else {                    // straddle tile (94 of 2256): predicated scalar
    for (int idx = threadIdx.x; idx < 64 * 128; idx += 256) {
      int row = idx >> 7, cc = idx & 127;
      int R = row0 + row, C = col0 + cc;
      u16 val = Dir[row * 136 + cc];
      if (C >= R) Abf[(size_t)R * NPAD + C] = val;
      if (C > R)  Abf[(size_t)C * NPAD + R] = val;
    }
  }
}

// partial[z] = Abf[:, zK:(z+1)K] @ hmT_all[:, zK:(z+1)K]^T  -> bf16 partials [2][NPAD][768]
__global__ __launch_bounds__(256, 2) void k_pvsk(const u16* __restrict__ Abf, const u16* __restrict__ hmT,
                                                 u16* __restrict__ part) {
  extern __shared__ u16 shp[];   // 2*(128*64) + 2*(128*64) u16 = 65536 B
  u16* As = shp;
  u16* Bs = shp + 2 * 128 * 64;
  int lane = threadIdx.x & 63, wave = threadIdx.x >> 6;
  int col0 = blockIdx.x * 128, row0 = blockIdx.y * 128, kb = blockIdx.z * (NPAD / 2);
  f32x4 acc[4][4];
  f32x4 z = {0.f, 0.f, 0.f, 0.f};
  for (int i = 0; i < 4; ++i) for (int j = 0; j < 4; ++j) acc[i][j] = z;
  gemm_loop_db<4>(Abf + (size_t)row0 * NPAD + kb, NPAD,
                  hmT + (size_t)col0 * NPAD + kb, NPAD, NPAD / 2, As, Bs, acc, lane, wave);
  u16* pp = part + (size_t)blockIdx.z * NPAD * (VV * HH);
  int wr = (wave >> 1) * 64, wc = (wave & 1) * 64, l15 = lane & 15, lq = lane >> 4;
#pragma unroll
  for (int i = 0; i < 4; ++i)
#pragma unroll
    for (int r = 0; r < 4; ++r) {
      int grow = row0 + wr + i * 16 + lq * 4 + r;
#pragma unroll
      for (int j = 0; j < 4; ++j) {
        int gcol = col0 + wc + j * 16 + l15;
        pp[(size_t)grow * (VV * HH) + gcol] = f2bf(acc[i][j][r]);
      }
    }
}

// newx = blend((p0+p1)/S, h); writes out_newx (f32) and nxb (bf16)
__global__ __launch_bounds__(256) void k_pvred(const u16* __restrict__ part, const float* __restrict__ S,
                                               const float* __restrict__ mT, const float* __restrict__ h,
                                               float* __restrict__ out_newx, u16* __restrict__ nxb) {
  int i = (blockIdx.x * 256 + threadIdx.x) * 4;   // over VV*NN*HH
  int v = i / (NN * HH);
  int rem = i - v * (NN * HH);
  int n = rem / HH;
  int j = rem - n * HH;
  int col = v * HH + j;
  u16x4 p0 = *(const u16x4*)(part + (size_t)n * (VV * HH) + col);
  u16x4 p1 = *(const u16x4*)(part + (size_t)NPAD * (VV * HH) + (size_t)n * (VV * HH) + col);
  float sc = 1.0f / (S[n] + 1e-9f);
  float mrow = mT[v * NPAD + n];
  float4 o;
  o.x = (bf2f(p0[0]) + bf2f(p1[0])) * sc;
  o.y = (bf2f(p0[1]) + bf2f(p1[1])) * sc;
  o.z = (bf2f(p0[2]) + bf2f(p1[2])) * sc;
  o.w = (bf2f(p0[3]) + bf2f(p1[3])) * sc;
  if (mrow != 0.0f) o = *(const float4*)(h + (size_t)(v * NPAD + n) * HH + j);
  *(float4*)(out_newx + (size_t)(v * NN + n) * HH + j) = o;
  u16x4 ob = { f2bf(o.x), f2bf(o.y), f2bf(o.z), f2bf(o.w) };
  *(u16x4*)(nxb + (size_t)(v * NPAD + n) * HH + j) = ob;
}

// x_new = leaky(new_x @ W_out^T + b_out), nan->0  [RT=2]
__global__ __launch_bounds__(256) void k_gemm3(const u16* __restrict__ nxb, const u16* __restrict__ woutb,
                                               const float* __restrict__ b_out, float* __restrict__ out_xnew) {
  __shared__ u16 As[64 * 64], Bs[128 * 64];
  int lane = threadIdx.x & 63, wave = threadIdx.x >> 6;
  int col0 = blockIdx.x * 128, row0 = blockIdx.y * 64, v = blockIdx.z;
  f32x4 acc[2][4];
  f32x4 z = {0.f, 0.f, 0.f, 0.f};
  for (int i = 0; i < 2; ++i) for (int j = 0; j < 4; ++j) acc[i][j] = z;
  gemm_loop<2>(nxb + (size_t)(v * NPAD + row0) * HH, HH,
               woutb + (size_t)(v * DD + col0) * HH, HH, HH, As, Bs, acc, lane, wave);
  int wr = (wave >> 1) * 32, wc = (wave & 1) * 64, l15 = lane & 15, lq = lane >> 4;
#pragma unroll
  for (int i = 0; i < 2; ++i)
#pragma unroll
    for (int r = 0; r < 4; ++r) {
      int grow = row0 + wr + i * 16 + lq * 4 + r;
      if (grow < NN) {
#pragma unroll
        for (int j = 0; j < 4; ++j) {
          int gcol = col0 + wc + j * 16 + l15;
          float val = leaky(acc[i][j][r] + b_out[v * DD + gcol]);
          if (val != val) val = 0.0f;
          out_xnew[(size_t)(v * NN + grow) * DD + gcol] = val;
        }
      }
    }
}

// y_n = sigmoid(y @ Wy^T + by)  [RT=2, double-buffered]
__global__ __launch_bounds__(256, 3) void k_ygemm(const u16* __restrict__ yb, const u16* __restrict__ wyb,
                                                  const float* __restrict__ by, float* __restrict__ out_yn) {
  __shared__ u16 As[2 * 64 * 64], Bs[2 * 128 * 64];
  int lane = threadIdx.x & 63, wave = threadIdx.x >> 6;
  int col0 = blockIdx.x * 128, row0 = blockIdx.y * 64;
  f32x4 acc[2][4];
  f32x4 z = {0.f, 0.f, 0.f, 0.f};
  for (int i = 0; i < 2; ++i) for (int j = 0; j < 4; ++j) acc[i][j] = z;
  gemm_loop_db<2>(yb + (size_t)row0 * DYY, DYY, wyb + (size_t)col0 * DYY, DYY, DYY, As, Bs, acc, lane, wave);
  int wr = (wave >> 1) * 32, wc = (wave & 1) * 64, l15 = lane & 15, lq = lane >> 4;
#pragma unroll
  for (int i = 0; i < 2; ++i)
#pragma unroll
    for (int r = 0; r < 4; ++r) {
      int grow = row0 + wr + i * 16 + lq * 4 + r;
      if (grow < NN) {
#pragma unroll
        for (int j = 0; j < 4; ++j) {
          int gcol = col0 + wc + j * 16 + l15;
          float val = acc[i][j][r] + by[gcol];
          out_yn[(size_t)grow * HH + gcol] = 1.0f / (1.0f + __expf(-val));
        }
      }
    }
}

// ---------------- launch ----------------

extern "C" void kernel_launch(void* const* d_in, const int* in_sizes, int n_in,
                              void* d_out, int out_size, void* d_ws, size_t ws_size,
                              hipStream_t stream) {
  const float* x    = (const float*)d_in[0];
  const float* y    = (const float*)d_in[1];
  const float* mask = (const float*)d_in[2];
  const float* W_in = (const float*)d_in[3];
  const float* b_in = (const float*)d_in[4];
  const float* W_out= (const float*)d_in[5];
  const float* b_out= (const float*)d_in[6];
  const float* Wy   = (const float*)d_in[7];
  const float* by   = (const float*)d_in[8];

  float* out_newx = (float*)d_out;
  float* out_xnew = out_newx + (size_t)VV * NN * HH;
  float* out_yn   = out_xnew + (size_t)VV * NN * DD;

  char* w = (char*)d_ws;
  size_t off = 0;
  auto alloc = [&](size_t bytes) -> void* {
    void* p = w + off;
    off += (bytes + 255) & ~(size_t)255;
    return p;
  };
  u16*   xb    = (u16*)alloc((size_t)VV * NPAD * DD * 2);
  u16*   yb    = (u16*)alloc((size_t)NPAD * DYY * 2);
  u16*   winb  = (u16*)alloc((size_t)VV * HH * DD * 2);
  u16*   woutb = (u16*)alloc((size_t)VV * DD * HH * 2);
  u16*   wyb   = (u16*)alloc((size_t)HH * DYY * 2);
  float* h     = (float*)alloc((size_t)VV * NPAD * HH * 4);
  u16*   qb    = (u16*)alloc((size_t)VV * NPAD * HH * 2);
  u16*   hmT   = (u16*)alloc((size_t)VV * HH * NPAD * 2);
  u16*   nxb   = (u16*)alloc((size_t)VV * NPAD * HH * 2);
  float* mT    = (float*)alloc((size_t)VV * NPAD * 4);
  float* S     = (float*)alloc((size_t)NPAD * 4);
  u16*   Abf   = (u16*)alloc((size_t)NPAD * NPAD * 2);
  // split-K partials (2 x NPAD x 768 bf16 = 18.48 MB) reuse xb, dead after k_gemm1
  u16*   pvp   = xb;
  (void)ws_size; (void)in_sizes; (void)n_in; (void)out_size;

  // conversions
  k_conv<<<384, 256, 0, stream>>>(W_in, winb, VV * HH * DD / 4);
  k_conv<<<384, 256, 0, stream>>>(W_out, woutb, VV * DD * HH / 4);
  k_conv<<<128, 256, 0, stream>>>(Wy, wyb, HH * DYY / 4);
  k_conv<<<3000, 256, 0, stream>>>(y, yb, NN * DYY / 4);
  k_convx<<<9000, 256, 0, stream>>>(x, xb);
  k_mt<<<(VV * NPAD + 255) / 256, 256, 0, stream>>>(mask, mT);
  hipMemsetAsync(S, 0, NPAD * sizeof(float), stream);

  // h, q, hmT
  k_gemm1<<<dim3(2, 94, 3), 256, 0, stream>>>(xb, winb, b_in, h);
  k_qprep<<<VV * NN, 256, 0, stream>>>(h, qb);
  k_hmt<<<dim3(94, 4, 3), dim3(64, 16), 0, stream>>>(h, mT, hmT);

  // attention (k_qk: upper-triangle tiles only; also accumulates row sums into S)
  k_qk<<<2256, 256, 2 * QK_HALF * sizeof(u16), stream>>>(qb, mT, Abf, S);
  k_pvsk<<<dim3(6, 47, 2), 256, 4 * 128 * 64 * sizeof(u16), stream>>>(Abf, hmT, pvp);
  k_pvred<<<4500, 256, 0, stream>>>(pvp, S, mT, h, out_newx, nxb);

  // outputs
  k_gemm3<<<dim3(4, 94, 3), 256, 0, stream>>>(nxb, woutb, b_out, out_xnew);
  k_ygemm<<<dim3(2, 94), 256, 0, stream>>>(yb, wyb, by, out_yn);
}

// Round 6
// 358.138 us; speedup vs baseline: 1.4530x; 1.0824x over previous
//
#include <hip/hip_runtime.h>

#define VV 3
#define NN 6000
#define DD 512
#define HH 256
#define DYY 512
#define NPAD 6016   // 47*128
#define QK_BK 32
#define QK_HALF (VV * 192 * QK_BK)   // u16 elems per staging buffer (36864 B)

typedef unsigned short u16;
typedef unsigned char u8;
typedef __bf16 bf16x8 __attribute__((ext_vector_type(8)));
typedef u16 u16x8 __attribute__((ext_vector_type(8)));
typedef float f32x4 __attribute__((ext_vector_type(4)));
typedef u16 u16x4 __attribute__((ext_vector_type(4)));
typedef unsigned int u32x4 __attribute__((ext_vector_type(4)));

__device__ __forceinline__ u16 f2bf(float f) {
  unsigned int b = __builtin_bit_cast(unsigned int, f);
  b += 0x7FFFu + ((b >> 16) & 1u);
  return (u16)(b >> 16);
}
__device__ __forceinline__ float bf2f(u16 u) {
  unsigned int b = ((unsigned int)u) << 16;
  return __builtin_bit_cast(float, b);
}
// manual OCP e4m3fn encode (RNE, clamp 448, subnormals) — no builtin dependency
__device__ __forceinline__ u8 f2fp8(float f) {
  unsigned int u = __builtin_bit_cast(unsigned int, f);
  u8 sign = (u >> 24) & 0x80;
  float af = __builtin_bit_cast(float, u & 0x7fffffffu);
  if (af >= 448.0f) return sign | 0x7E;
  if (af < 0.015625f) {                      // subnormal: round af*2^9
    int m = (int)(af * 512.0f + 0.5f);
    return sign | (u8)m;                     // m==8 -> 0x08 == 2^-6, correct
  }
  unsigned int mant = u & 0x7fffff;
  unsigned int exp = (u >> 23) & 0xff;       // 121..135
  unsigned int r = ((exp << 23) | mant) + 0x7FFFFu + ((mant >> 20) & 1u);
  exp = r >> 23; mant = (r >> 20) & 7u;
  return sign | (u8)(((exp - 120u) << 3) | mant);
}
__device__ __forceinline__ float fp82f(u8 b) {
  int e = (b >> 3) & 15, m = b & 7;
  float v = e ? __builtin_bit_cast(float, (unsigned)((e + 120) << 23 | (m << 20)))
              : (float)m * 0.001953125f;
  return (b & 0x80) ? -v : v;
}
__device__ __forceinline__ float leaky(float v) { return v >= 0.0f ? v : 0.1f * v; }

// ---- stage ROWS x DEPTH bf16 tile: global row-major (ld elems) -> LDS [ROWS][DEPTH]
template<int ROWS, int DEPTH = 64>
__device__ __forceinline__ void stage(const u16* __restrict__ g, int ld, u16* s, int wave, int lane) {
  constexpr int LPR = DEPTH / 8;   // lanes per row (16B each)
  constexpr int RPC = 64 / LPR;    // rows per chunk
  constexpr int PER = ROWS / 4;    // rows per wave
  const u16* gp = g + (wave * PER + lane / LPR) * ld + (lane % LPR) * 8;
  u16* sp = s + wave * PER * DEPTH;
#pragma unroll
  for (int ch = 0; ch < PER / RPC; ++ch) {
    __builtin_amdgcn_global_load_lds(
        (const __attribute__((address_space(1))) void*)(gp + ch * RPC * ld),
        (__attribute__((address_space(3))) void*)(sp + ch * RPC * DEPTH), 16, 0, 0);
  }
}

// ---- fp8 stage: ROWS x 64-byte rows with 16-B-chunk XOR swizzle (bank-conflict-free reads)
__device__ __forceinline__ int swz4(int r) { return (r & 3) ^ ((r >> 2) & 3); }
template<int ROWS>
__device__ __forceinline__ void stage8(const u8* __restrict__ g, int ld, u8* s, int wave, int lane) {
  constexpr int PER = ROWS / 4;    // rows per wave (4 lanes/row, 16 rows per 64-lane chunk)
  int rin = lane >> 2, c = lane & 3;
#pragma unroll
  for (int ch = 0; ch < PER / 16; ++ch) {
    int rloc = wave * PER + ch * 16 + rin;
    const u8* gp = g + (size_t)rloc * ld + ((c ^ swz4(rloc)) << 4);
    u8* sp = s + (wave * PER + ch * 16) * 64;   // wave-uniform; lane lands at +16B*lane
    __builtin_amdgcn_global_load_lds(
        (const __attribute__((address_space(1))) void*)gp,
        (__attribute__((address_space(3))) void*)sp, 16, 0, 0);
  }
}

// ---- wave computes (RT*16) x 64 outputs; block = 4 waves in 2x2 -> (RT*32) x 128 tile
template<int RT, int DEPTH = 64>
__device__ __forceinline__ void mfma_step(const u16* As, const u16* Bs, f32x4 (*acc)[4], int lane, int wave) {
  const int wr = (wave >> 1) * (RT * 16);
  const int wc = (wave & 1) * 64;
  const int l15 = lane & 15;
  const int lq = lane >> 4;
#pragma unroll
  for (int kk = 0; kk < DEPTH; kk += 32) {
    bf16x8 a[RT], b[4];
#pragma unroll
    for (int i = 0; i < RT; ++i)
      a[i] = *(const bf16x8*)(As + (wr + i * 16 + l15) * DEPTH + kk + lq * 8);
#pragma unroll
    for (int j = 0; j < 4; ++j)
      b[j] = *(const bf16x8*)(Bs + (wc + j * 16 + l15) * DEPTH + kk + lq * 8);
#pragma unroll
    for (int i = 0; i < RT; ++i)
#pragma unroll
      for (int j = 0; j < 4; ++j)
        acc[i][j] = __builtin_amdgcn_mfma_f32_16x16x32_bf16(a[i], b[j], acc[i][j], 0, 0, 0);
  }
}

// fp8 MFMA step: 128x128 tile, 64 K-elems (64 B) per slice, swizzled LDS
__device__ __forceinline__ void mfma_step8(const u8* As, const u8* Bs, f32x4 (*acc)[4], int lane, int wave) {
  const int wr = (wave >> 1) * 64;
  const int wc = (wave & 1) * 64;
  const int l15 = lane & 15, lq = lane >> 4;
#pragma unroll
  for (int kk = 0; kk < 64; kk += 32) {
    long a[4], b[4];
    int gch = (kk >> 4) + (lq >> 1), half = (lq & 1) << 3;
#pragma unroll
    for (int i = 0; i < 4; ++i) {
      int r = wr + i * 16 + l15;
      a[i] = *(const long*)(As + r * 64 + ((gch ^ swz4(r)) << 4) + half);
    }
#pragma unroll
    for (int j = 0; j < 4; ++j) {
      int r = wc + j * 16 + l15;
      b[j] = *(const long*)(Bs + r * 64 + ((gch ^ swz4(r)) << 4) + half);
    }
#pragma unroll
    for (int i = 0; i < 4; ++i)
#pragma unroll
      for (int j = 0; j < 4; ++j)
        acc[i][j] = __builtin_amdgcn_mfma_f32_16x16x32_fp8_fp8(a[i], b[j], acc[i][j], 0, 0, 0);
  }
}

// single-buffered K-loop
template<int RT>
__device__ __forceinline__ void gemm_loop(const u16* __restrict__ A, int lda,
                                          const u16* __restrict__ B, int ldb, int K,
                                          u16* As, u16* Bs, f32x4 (*acc)[4], int lane, int wave) {
  for (int k0 = 0; k0 < K; k0 += 64) {
    stage<RT * 32>(A + k0, lda, As, wave, lane);
    stage<128>(B + k0, ldb, Bs, wave, lane);
    __syncthreads();
    mfma_step<RT>(As, Bs, acc, lane, wave);
    __syncthreads();
  }
}

// double-buffered K-loop
template<int RT>
__device__ __forceinline__ void gemm_loop_db(const u16* __restrict__ A, int lda,
                                             const u16* __restrict__ B, int ldb, int K,
                                             u16* As, u16* Bs, f32x4 (*acc)[4], int lane, int wave) {
  const int niter = K / 64;
  stage<RT * 32>(A, lda, As, wave, lane);
  stage<128>(B, ldb, Bs, wave, lane);
  for (int it = 0; it < niter; ++it) {
    __syncthreads();
    int nb = (it + 1) & 1;
    if (it + 1 < niter) {
      stage<RT * 32>(A + (it + 1) * 64, lda, As + nb * RT * 32 * 64, wave, lane);
      stage<128>(B + (it + 1) * 64, ldb, Bs + nb * 128 * 64, wave, lane);
    }
    int cb = it & 1;
    mfma_step<RT>(As + cb * RT * 32 * 64, Bs + cb * 128 * 64, acc, lane, wave);
  }
  __syncthreads();
}

// ---------------- elementwise / prep kernels ----------------

__global__ __launch_bounds__(256) void k_conv(const float* __restrict__ in, u16* __restrict__ out, int n4) {
  int i = blockIdx.x * 256 + threadIdx.x;
  if (i >= n4) return;
  float4 f = ((const float4*)in)[i];
  u16x4 o = { f2bf(f.x), f2bf(f.y), f2bf(f.z), f2bf(f.w) };
  *(u16x4*)(out + i * 4) = o;
}

__global__ __launch_bounds__(256) void k_convx(const float* __restrict__ x, u16* __restrict__ xb) {
  int i = blockIdx.x * 256 + threadIdx.x;
  if (i >= VV * NN * DD / 4) return;
  int idx = i * 4;
  int v = idx / (NN * DD);
  int rem = idx - v * (NN * DD);
  int n = rem / DD;
  int d = rem - n * DD;
  float4 f = *(const float4*)(x + idx);
  u16x4 o = { f2bf(f.x), f2bf(f.y), f2bf(f.z), f2bf(f.w) };
  *(u16x4*)(xb + (size_t)(v * NPAD + n) * DD + d) = o;
}

__global__ __launch_bounds__(256) void k_mt(const float* __restrict__ mask, float* __restrict__ mT) {
  int i = blockIdx.x * 256 + threadIdx.x;
  if (i >= VV * NPAD) return;
  int v = i / NPAD, n = i - v * NPAD;
  mT[i] = (n < NN) ? mask[n * VV + v] : 0.0f;
}

__global__ __launch_bounds__(256) void k_qprep(const float* __restrict__ h, u16* __restrict__ qb) {
  int b = blockIdx.x;
  int v = b / NN, n = b - v * NN;
  int t = threadIdx.x;
  float val = h[(size_t)(v * NPAD + n) * HH + t];
  float ss = val * val;
#pragma unroll
  for (int o = 32; o > 0; o >>= 1) ss += __shfl_down(ss, o, 64);
  __shared__ float red[4];
  if ((t & 63) == 0) red[t >> 6] = ss;
  __syncthreads();
  float inv = 1.0f / fmaxf(sqrtf(red[0] + red[1] + red[2] + red[3]), 1e-12f);
  qb[(size_t)(v * NPAD + n) * HH + t] = f2bf(val * inv);
}

// hmT[v][j][m] = mT[v][m]*h[v][m][j] (fp8 e4m3, zero for m>=NN)
__global__ __launch_bounds__(1024) void k_hmt(const float* __restrict__ h, const float* __restrict__ mT,
                                              u8* __restrict__ hmT) {
  __shared__ float t[64][65];
  int m0 = blockIdx.x * 64, j0 = blockIdx.y * 64, v = blockIdx.z;
  int tx = threadIdx.x, ty = threadIdx.y;
#pragma unroll
  for (int p = 0; p < 4; ++p) {
    int ml = ty + p * 16;
    int m = m0 + ml;
    float val = 0.0f;
    if (m < NN) val = mT[v * NPAD + m] * h[(size_t)(v * NPAD + m) * HH + j0 + tx];
    t[ml][tx] = val;
  }
  __syncthreads();
#pragma unroll
  for (int p = 0; p < 4; ++p) {
    int j = j0 + ty + p * 16;
    hmT[(size_t)(v * HH + j) * NPAD + m0 + tx] = f2fp8(t[tx][ty + p * 16]);
  }
}

// ---------------- GEMM kernels ----------------

__global__ __launch_bounds__(256, 3) void k_gemm1(const u16* __restrict__ xb, const u16* __restrict__ winb,
                                                  const float* __restrict__ b_in, float* __restrict__ h) {
  __shared__ u16 As[2 * 64 * 64], Bs[2 * 128 * 64];
  int lane = threadIdx.x & 63, wave = threadIdx.x >> 6;
  int col0 = blockIdx.x * 128, row0 = blockIdx.y * 64, v = blockIdx.z;
  f32x4 acc[2][4];
  f32x4 z = {0.f, 0.f, 0.f, 0.f};
  for (int i = 0; i < 2; ++i) for (int j = 0; j < 4; ++j) acc[i][j] = z;
  gemm_loop_db<2>(xb + (size_t)(v * NPAD + row0) * DD, DD,
                  winb + (size_t)(v * HH + col0) * DD, DD, DD, As, Bs, acc, lane, wave);
  int wr = (wave >> 1) * 32, wc = (wave & 1) * 64, l15 = lane & 15, lq = lane >> 4;
#pragma unroll
  for (int i = 0; i < 2; ++i)
#pragma unroll
    for (int r = 0; r < 4; ++r) {
      int grow = row0 + wr + i * 16 + lq * 4 + r;
      if (grow < NN) {
#pragma unroll
        for (int j = 0; j < 4; ++j) {
          int gcol = col0 + wc + j * 16 + l15;
          h[(size_t)(v * NPAD + grow) * HH + gcol] = leaky(acc[i][j][r] + b_in[v * HH + gcol]);
        }
      }
    }
}

// A = max_v mask*exp(q_v q_v^T / beta), diag zeroed -> fp8 e4m3; row sums into S (from
// dequantized values). Upper-triangle tiles only; dbuf staging; vectorized dual write.
__global__ __launch_bounds__(256, 2) void k_qk(const u16* __restrict__ qb, const float* __restrict__ mT,
                                               u8* __restrict__ Abf, float* __restrict__ S) {
  extern __shared__ u16 sh[];   // 2 * QK_HALF u16 = 73728 B
  int lane = threadIdx.x & 63, wave = threadIdx.x >> 6;
  int bid = blockIdx.x;
  int x = (int)((sqrtf((float)(4 * bid + 1)) - 1.0f) * 0.5f);
  while ((x + 1) * (x + 2) <= bid) ++x;
  while (x * (x + 1) > bid) --x;
  int y = bid - x * (x + 1);
  int col0 = x * 128, row0 = y * 64;

  f32x4 z = {0.f, 0.f, 0.f, 0.f};
  f32x4 acc[VV][2][4];
  for (int v = 0; v < VV; ++v)
    for (int i = 0; i < 2; ++i)
      for (int j = 0; j < 4; ++j) acc[v][i][j] = z;

  auto qk_stage = [&](int k0, u16* buf) {
#pragma unroll
    for (int v = 0; v < VV; ++v) {
      stage<64, QK_BK>(qb + (size_t)(v * NPAD + row0) * HH + k0, HH, buf + v * 64 * QK_BK, wave, lane);
      stage<128, QK_BK>(qb + (size_t)(v * NPAD + col0) * HH + k0, HH,
                        buf + VV * 64 * QK_BK + v * 128 * QK_BK, wave, lane);
    }
  };

  qk_stage(0, sh);
#pragma unroll
  for (int it = 0; it < HH / QK_BK; ++it) {
    __syncthreads();
    if (it + 1 < HH / QK_BK)
      qk_stage((it + 1) * QK_BK, sh + ((it + 1) & 1) * QK_HALF);
    u16* cur = sh + (it & 1) * QK_HALF;
#pragma unroll
    for (int v = 0; v < VV; ++v)
      mfma_step<2, QK_BK>(cur + v * 64 * QK_BK, cur + VV * 64 * QK_BK + v * 128 * QK_BK,
                          acc[v], lane, wave);
  }
  __syncthreads();

  // epilogue: Dir [64][144] u8 (direct tile), Tr [128][80] u8 (mirror), S sums
  u8* Dir = (u8*)sh;
  u8* Tr  = (u8*)sh + 64 * 144;
  int wr = (wave >> 1) * 32, wc = (wave & 1) * 64, l15 = lane & 15, lq = lane >> 4;
  float mc[VV][4];
#pragma unroll
  for (int v = 0; v < VV; ++v)
#pragma unroll
    for (int j = 0; j < 4; ++j) mc[v][j] = mT[v * NPAD + col0 + wc + j * 16 + l15];
  float cs[4] = {0.f, 0.f, 0.f, 0.f};
#pragma unroll
  for (int i = 0; i < 2; ++i)
#pragma unroll
    for (int r = 0; r < 4; ++r) {
      int lrow = wr + i * 16 + lq * 4 + r;
      int grow = row0 + lrow;
      float mr0 = mT[grow];
      float mr1 = mT[NPAD + grow];
      float mr2 = mT[2 * NPAD + grow];
      float rs = 0.0f;
#pragma unroll
      for (int j = 0; j < 4; ++j) {
        int lcol = wc + j * 16 + l15;
        int gcol = col0 + lcol;
        float e0 = (mr0 * mc[0][j] != 0.0f) ? __expf(acc[0][i][j][r] * 5.0f) : 0.0f;
        float e1 = (mr1 * mc[1][j] != 0.0f) ? __expf(acc[1][i][j][r] * 5.0f) : 0.0f;
        float e2 = (mr2 * mc[2][j] != 0.0f) ? __expf(acc[2][i][j][r] * 5.0f) : 0.0f;
        float val = fmaxf(fmaxf(e0, e1), e2);
        if (grow == gcol) val = 0.0f;
        u8 q = f2fp8(val);
        float dq = fp82f(q);
        Dir[lrow * 144 + lcol] = q;
        bool strict = gcol > grow;
        Tr[lcol * 80 + lrow] = strict ? q : (u8)0;
        if (gcol >= grow) rs += dq;
        if (strict) cs[j] += dq;
      }
#pragma unroll
      for (int m = 1; m < 16; m <<= 1) rs += __shfl_xor(rs, m, 64);
      if (l15 == 0 && rs != 0.0f) atomicAdd(&S[grow], rs);
    }
#pragma unroll
  for (int j = 0; j < 4; ++j) {
    float c = cs[j];
    c += __shfl_xor(c, 16, 64);
    c += __shfl_xor(c, 32, 64);
    if (lq == 0 && c != 0.0f) atomicAdd(&S[col0 + wc + j * 16 + l15], c);
  }
  __syncthreads();
  if (col0 >= row0 + 64) {   // fully-upper tile: 16-B vector stores
    int c8 = threadIdx.x & 7, rr = threadIdx.x >> 3;
#pragma unroll
    for (int p = 0; p < 2; ++p) {
      int row = rr + p * 32;
      u32x4 ch = *(const u32x4*)(Dir + row * 144 + c8 * 16);
      *(u32x4*)(Abf + (size_t)(row0 + row) * NPAD + col0 + c8 * 16) = ch;
    }
    int c = threadIdx.x & 3; rr = threadIdx.x >> 2;
#pragma unroll
    for (int p = 0; p < 2; ++p) {
      int cc = rr + p * 64;
      u32x4 ch = *(const u32x4*)(Tr + cc * 80 + c * 16);
      *(u32x4*)(Abf + (size_t)(col0 + cc) * NPAD + row0 + c * 16) = ch;
    }
  } else {                    // straddle tile: predicated scalar
    for (int idx = threadIdx.x; idx < 64 * 128; idx += 256) {
      int row = idx >> 7, cc = idx & 127;
      int R = row0 + row, C = col0 + cc;
      u8 val = Dir[row * 144 + cc];
      if (C >= R) Abf[(size_t)R * NPAD + C] = val;
      if (C > R)  Abf[(size_t)C * NPAD + R] = val;
    }
  }
}

// partial[z] = Abf[:, zK:(z+1)K] @ hmT_all[:, zK:(z+1)K]^T  (fp8 operands, f32 acc,
// bf16 partials). XCD-swizzled flat grid: all 12 blocks of a row-panel share an XCD.
__global__ __launch_bounds__(256, 4) void k_pvsk(const u8* __restrict__ Abf, const u8* __restrict__ hmT,
                                                 u16* __restrict__ part) {
  __shared__ u8 sh8[2 * 2 * 128 * 64];   // [buf][A/B][128][64] = 32 KB
  int lane = threadIdx.x & 63, wave = threadIdx.x >> 6;
  int bid = blockIdx.x;                  // 576 (12 dummy)
  int xcd = bid & 7, s = bid >> 3;
  int row = (s / 12) * 8 + xcd;
  if (row >= 47) return;
  int k = s % 12;
  int col0 = (k % 6) * 128, row0 = row * 128, kb = (k / 6) * (NPAD / 2);

  f32x4 acc[4][4];
  f32x4 z = {0.f, 0.f, 0.f, 0.f};
  for (int i = 0; i < 4; ++i) for (int j = 0; j < 4; ++j) acc[i][j] = z;

  const u8* Ap = Abf + (size_t)row0 * NPAD + kb;
  const u8* Bp = hmT + (size_t)col0 * NPAD + kb;
  auto pv_stage = [&](int it, int buf) {
    u8* base = sh8 + buf * 16384;
    stage8<128>(Ap + it * 64, NPAD, base, wave, lane);
    stage8<128>(Bp + it * 64, NPAD, base + 8192, wave, lane);
  };
  const int niter = (NPAD / 2) / 64;   // 47
  pv_stage(0, 0);
  for (int it = 0; it < niter; ++it) {
    __syncthreads();
    if (it + 1 < niter) pv_stage(it + 1, (it + 1) & 1);
    u8* cur = sh8 + (it & 1) * 16384;
    mfma_step8(cur, cur + 8192, acc, lane, wave);
  }

  u16* pp = part + (size_t)(k / 6) * NPAD * (VV * HH);
  int wr = (wave >> 1) * 64, wc = (wave & 1) * 64, l15 = lane & 15, lq = lane >> 4;
#pragma unroll
  for (int i = 0; i < 4; ++i)
#pragma unroll
    for (int r = 0; r < 4; ++r) {
      int grow = row0 + wr + i * 16 + lq * 4 + r;
#pragma unroll
      for (int j = 0; j < 4; ++j) {
        int gcol = col0 + wc + j * 16 + l15;
        pp[(size_t)grow * (VV * HH) + gcol] = f2bf(acc[i][j][r]);
      }
    }
}

// newx = blend((p0+p1)/S, h); writes out_newx (f32) and nxb (bf16)
__global__ __launch_bounds__(256) void k_pvred(const u16* __restrict__ part, const float* __restrict__ S,
                                               const float* __restrict__ mT, const float* __restrict__ h,
                                               float* __restrict__ out_newx, u16* __restrict__ nxb) {
  int i = (blockIdx.x * 256 + threadIdx.x) * 4;
  int v = i / (NN * HH);
  int rem = i - v * (NN * HH);
  int n = rem / HH;
  int j = rem - n * HH;
  int col = v * HH + j;
  u16x4 p0 = *(const u16x4*)(part + (size_t)n * (VV * HH) + col);
  u16x4 p1 = *(const u16x4*)(part + (size_t)NPAD * (VV * HH) + (size_t)n * (VV * HH) + col);
  float sc = 1.0f / (S[n] + 1e-9f);
  float mrow = mT[v * NPAD + n];
  float4 o;
  o.x = (bf2f(p0[0]) + bf2f(p1[0])) * sc;
  o.y = (bf2f(p0[1]) + bf2f(p1[1])) * sc;
  o.z = (bf2f(p0[2]) + bf2f(p1[2])) * sc;
  o.w = (bf2f(p0[3]) + bf2f(p1[3])) * sc;
  if (mrow != 0.0f) o = *(const float4*)(h + (size_t)(v * NPAD + n) * HH + j);
  *(float4*)(out_newx + (size_t)(v * NN + n) * HH + j) = o;
  u16x4 ob = { f2bf(o.x), f2bf(o.y), f2bf(o.z), f2bf(o.w) };
  *(u16x4*)(nxb + (size_t)(v * NPAD + n) * HH + j) = ob;
}

// x_new = leaky(new_x @ W_out^T + b_out), nan->0  [RT=2, double-buffered]
__global__ __launch_bounds__(256, 3) void k_gemm3(const u16* __restrict__ nxb, const u16* __restrict__ woutb,
                                                  const float* __restrict__ b_out, float* __restrict__ out_xnew) {
  __shared__ u16 As[2 * 64 * 64], Bs[2 * 128 * 64];
  int lane = threadIdx.x & 63, wave = threadIdx.x >> 6;
  int col0 = blockIdx.x * 128, row0 = blockIdx.y * 64, v = blockIdx.z;
  f32x4 acc[2][4];
  f32x4 z = {0.f, 0.f, 0.f, 0.f};
  for (int i = 0; i < 2; ++i) for (int j = 0; j < 4; ++j) acc[i][j] = z;
  gemm_loop_db<2>(nxb + (size_t)(v * NPAD + row0) * HH, HH,
                  woutb + (size_t)(v * DD + col0) * HH, HH, HH, As, Bs, acc, lane, wave);
  int wr = (wave >> 1) * 32, wc = (wave & 1) * 64, l15 = lane & 15, lq = lane >> 4;
#pragma unroll
  for (int i = 0; i < 2; ++i)
#pragma unroll
    for (int r = 0; r < 4; ++r) {
      int grow = row0 + wr + i * 16 + lq * 4 + r;
      if (grow < NN) {
#pragma unroll
        for (int j = 0; j < 4; ++j) {
          int gcol = col0 + wc + j * 16 + l15;
          float val = leaky(acc[i][j][r] + b_out[v * DD + gcol]);
          if (val != val) val = 0.0f;
          out_xnew[(size_t)(v * NN + grow) * DD + gcol] = val;
        }
      }
    }
}

// y_n = sigmoid(y @ Wy^T + by)  [RT=2, double-buffered]
__global__ __launch_bounds__(256, 3) void k_ygemm(const u16* __restrict__ yb, const u16* __restrict__ wyb,
                                                  const float* __restrict__ by, float* __restrict__ out_yn) {
  __shared__ u16 As[2 * 64 * 64], Bs[2 * 128 * 64];
  int lane = threadIdx.x & 63, wave = threadIdx.x >> 6;
  int col0 = blockIdx.x * 128, row0 = blockIdx.y * 64;
  f32x4 acc[2][4];
  f32x4 z = {0.f, 0.f, 0.f, 0.f};
  for (int i = 0; i < 2; ++i) for (int j = 0; j < 4; ++j) acc[i][j] = z;
  gemm_loop_db<2>(yb + (size_t)row0 * DYY, DYY, wyb + (size_t)col0 * DYY, DYY, DYY, As, Bs, acc, lane, wave);
  int wr = (wave >> 1) * 32, wc = (wave & 1) * 64, l15 = lane & 15, lq = lane >> 4;
#pragma unroll
  for (int i = 0; i < 2; ++i)
#pragma unroll
    for (int r = 0; r < 4; ++r) {
      int grow = row0 + wr + i * 16 + lq * 4 + r;
      if (grow < NN) {
#pragma unroll
        for (int j = 0; j < 4; ++j) {
          int gcol = col0 + wc + j * 16 + l15;
          float val = acc[i][j][r] + by[gcol];
          out_yn[(size_t)grow * HH + gcol] = 1.0f / (1.0f + __expf(-val));
        }
      }
    }
}

// ---------------- launch ----------------

extern "C" void kernel_launch(void* const* d_in, const int* in_sizes, int n_in,
                              void* d_out, int out_size, void* d_ws, size_t ws_size,
                              hipStream_t stream) {
  const float* x    = (const float*)d_in[0];
  const float* y    = (const float*)d_in[1];
  const float* mask = (const float*)d_in[2];
  const float* W_in = (const float*)d_in[3];
  const float* b_in = (const float*)d_in[4];
  const float* W_out= (const float*)d_in[5];
  const float* b_out= (const float*)d_in[6];
  const float* Wy   = (const float*)d_in[7];
  const float* by   = (const float*)d_in[8];

  float* out_newx = (float*)d_out;
  float* out_xnew = out_newx + (size_t)VV * NN * HH;
  float* out_yn   = out_xnew + (size_t)VV * NN * DD;

  char* w = (char*)d_ws;
  size_t off = 0;
  auto alloc = [&](size_t bytes) -> void* {
    void* p = w + off;
    off += (bytes + 255) & ~(size_t)255;
    return p;
  };
  u16*   xb    = (u16*)alloc((size_t)VV * NPAD * DD * 2);
  u16*   yb    = (u16*)alloc((size_t)NPAD * DYY * 2);
  u16*   winb  = (u16*)alloc((size_t)VV * HH * DD * 2);
  u16*   woutb = (u16*)alloc((size_t)VV * DD * HH * 2);
  u16*   wyb   = (u16*)alloc((size_t)HH * DYY * 2);
  float* h     = (float*)alloc((size_t)VV * NPAD * HH * 4);
  u16*   qb    = (u16*)alloc((size_t)VV * NPAD * HH * 2);
  u8*    hmT   = (u8*)alloc((size_t)VV * HH * NPAD);
  u16*   nxb   = (u16*)alloc((size_t)VV * NPAD * HH * 2);
  float* mT    = (float*)alloc((size_t)VV * NPAD * 4);
  float* S     = (float*)alloc((size_t)NPAD * 4);
  u8*    Abf   = (u8*)alloc((size_t)NPAD * NPAD);
  // split-K partials (2 x NPAD x 768 bf16 = 18.48 MB) reuse xb, dead after k_gemm1
  u16*   pvp   = xb;
  (void)ws_size; (void)in_sizes; (void)n_in; (void)out_size;

  // conversions
  k_conv<<<384, 256, 0, stream>>>(W_in, winb, VV * HH * DD / 4);
  k_conv<<<384, 256, 0, stream>>>(W_out, woutb, VV * DD * HH / 4);
  k_conv<<<128, 256, 0, stream>>>(Wy, wyb, HH * DYY / 4);
  k_conv<<<3000, 256, 0, stream>>>(y, yb, NN * DYY / 4);
  k_convx<<<9000, 256, 0, stream>>>(x, xb);
  k_mt<<<(VV * NPAD + 255) / 256, 256, 0, stream>>>(mask, mT);
  hipMemsetAsync(S, 0, NPAD * sizeof(float), stream);

  // h, q, hmT
  k_gemm1<<<dim3(2, 94, 3), 256, 0, stream>>>(xb, winb, b_in, h);
  k_qprep<<<VV * NN, 256, 0, stream>>>(h, qb);
  k_hmt<<<dim3(94, 4, 3), dim3(64, 16), 0, stream>>>(h, mT, hmT);

  // attention
  k_qk<<<2256, 256, 2 * QK_HALF * sizeof(u16), stream>>>(qb, mT, Abf, S);
  k_pvsk<<<576, 256, 0, stream>>>(Abf, hmT, pvp);
  k_pvred<<<4500, 256, 0, stream>>>(pvp, S, mT, h, out_newx, nxb);

  // outputs
  k_gemm3<<<dim3(4, 94, 3), 256, 0, stream>>>(nxb, woutb, b_out, out_xnew);
  k_ygemm<<<dim3(2, 94), 256, 0, stream>>>(yb, wyb, by, out_yn);
}